// Round 2
// baseline (1305.581 us; speedup 1.0000x reference)
//
#include <hip/hip_runtime.h>
#include <stdint.h>

// Problem constants
#define BB 2
#define TT 2048
#define DD 2048
#define HH 16
#define HD 2048     // H*Dk = H*Dv
#define MM 4096     // B*T
#define SCH 16      // scan chunk steps

typedef float f32x4 __attribute__((ext_vector_type(4)));
typedef __bf16 bf16x8 __attribute__((ext_vector_type(8)));
typedef unsigned short u16x4 __attribute__((ext_vector_type(4)));
typedef unsigned int u32x2 __attribute__((ext_vector_type(2)));

__device__ __forceinline__ unsigned short f2b(float f) {
  unsigned int u = __float_as_uint(f);
  u += 0x7FFFu + ((u >> 16) & 1u);   // RNE
  return (unsigned short)(u >> 16);
}

__device__ __forceinline__ void async_ld16(const void* g, void* l) {
  typedef __attribute__((address_space(3))) void as3_t;
  typedef const __attribute__((address_space(1))) void as1_t;
  // NOTE: LDS arg must be WAVE-UNIFORM base; HW adds lane*16 itself.
  __builtin_amdgcn_global_load_lds((as1_t*)(uintptr_t)g,
                                   (as3_t*)(unsigned int)(uintptr_t)l, 16, 0, 0);
}

// ---- DPP 16-lane all-reduce (VALU-pipe; avoids ds_swizzle ~120cyc latency) ----
template <int CTRL>
__device__ __forceinline__ float dpp_add(float x) {
  int y = __builtin_amdgcn_update_dpp(0, __float_as_int(x), CTRL, 0xF, 0xF, false);
  return x + __int_as_float(y);
}
__device__ __forceinline__ float reduce16(float x) {
  x = dpp_add<0xB1>(x);    // quad_perm [1,0,3,2]  (xor 1)
  x = dpp_add<0x4E>(x);    // quad_perm [2,3,0,1]  (xor 2)
  x = dpp_add<0x124>(x);   // row_ror:4
  x = dpp_add<0x128>(x);   // row_ror:8
  return x;                // all 16 lanes hold the row sum
}

// ---- lane <-> lane^32 exchange-and-add via v_permlane32_swap_b32 (VALU pipe) ----
// Builtin (not raw asm): with raw asm and a=b=x the register allocator
// coalesces both "+v" operands into ONE register (same SSA value), emitting
// v_permlane32_swap_b32 v5, v5 -> every lane gets 2*x[l^32]. The intrinsic is
// value-defined, so the compiler materializes two registers. Result pair:
// r.x = {x[0:31], x[0:31]}, r.y = {x[32:63], x[32:63]} => r.x+r.y = x[l]+x[l^32].
__device__ __forceinline__ float swap32_sum(float x) {
  u32x2 r = __builtin_amdgcn_permlane32_swap(__float_as_uint(x),
                                             __float_as_uint(x), false, false);
  return __uint_as_float(r.x) + __uint_as_float(r.y);
}

// ---------------- cast f32 -> bf16 (vectorized x4) ----------------
__global__ __launch_bounds__(256) void cast_f32_bf16(const float* __restrict__ in,
                                                     unsigned short* __restrict__ out,
                                                     int n4) {
  int i = blockIdx.x * 256 + threadIdx.x;
  if (i >= n4) return;
  f32x4 v = *(const f32x4*)(in + (size_t)i * 4);
  u16x4 r;
  #pragma unroll
  for (int j = 0; j < 4; j++) r[j] = f2b(v[j]);
  *(u16x4*)(out + (size_t)i * 4) = r;
}

// ---------------- transpose + cast: in f32 [R,C] -> out bf16 [C,R] ----------------
__global__ __launch_bounds__(256) void transpose_cast(const float* __restrict__ in,
                                                      unsigned short* __restrict__ out,
                                                      int R, int C) {
  __shared__ float tile[32][33];
  int bx = blockIdx.x * 32, by = blockIdx.y * 32;
  int tx = threadIdx.x, ty = threadIdx.y;
  #pragma unroll
  for (int i = 0; i < 32; i += 8)
    tile[ty + i][tx] = in[(size_t)(by + ty + i) * C + bx + tx];
  __syncthreads();
  #pragma unroll
  for (int i = 0; i < 32; i += 8)
    out[(size_t)(bx + ty + i) * R + by + tx] = f2b(tile[tx][ty + i]);
}

// ---------------- bf16 GEMM: C[M,N] f32 = A[M,K] @ Bt[N,K]^T (+bias) ----------------
__global__ __launch_bounds__(256) void gemm_bf16(const unsigned short* __restrict__ A,
                                                 const unsigned short* __restrict__ Bt,
                                                 float* __restrict__ C,
                                                 const float* __restrict__ bias,
                                                 int M, int N, int K) {
  __shared__ __align__(16) unsigned short As[128 * 32];
  __shared__ __align__(16) unsigned short Bs[128 * 32];
  int tid = threadIdx.x;
  int l = tid & 63, w = tid >> 6;
  int row0 = blockIdx.y * 128, col0 = blockIdx.x * 128;
  int wm = (w >> 1) * 64, wn = (w & 1) * 64;
  const f32x4 fz = {0.f, 0.f, 0.f, 0.f};
  f32x4 acc[4][4];
  #pragma unroll
  for (int i = 0; i < 4; i++)
    #pragma unroll
    for (int j = 0; j < 4; j++) acc[i][j] = fz;

  int srow = l >> 2, skoff = (l & 3) * 8;
  int quad = l >> 4, mrow = l & 15;

  for (int kt = 0; kt < K; kt += 32) {
    #pragma unroll
    for (int i = 0; i < 2; i++) {
      int c = w * 2 + i;
      const unsigned short* gA = A + (size_t)(row0 + c * 16 + srow) * K + kt + skoff;
      const unsigned short* gB = Bt + (size_t)(col0 + c * 16 + srow) * K + kt + skoff;
      async_ld16(gA, As + c * 512);
      async_ld16(gB, Bs + c * 512);
    }
    __syncthreads();
    bf16x8 af[4], bfr[4];
    #pragma unroll
    for (int i = 0; i < 4; i++)
      af[i] = *(const bf16x8*)(As + (wm + i * 16 + mrow) * 32 + quad * 8);
    #pragma unroll
    for (int j = 0; j < 4; j++)
      bfr[j] = *(const bf16x8*)(Bs + (wn + j * 16 + mrow) * 32 + quad * 8);
    #pragma unroll
    for (int i = 0; i < 4; i++)
      #pragma unroll
      for (int j = 0; j < 4; j++)
        acc[i][j] = __builtin_amdgcn_mfma_f32_16x16x32_bf16(af[i], bfr[j], acc[i][j], 0, 0, 0);
    __syncthreads();
  }
  #pragma unroll
  for (int i = 0; i < 4; i++) {
    #pragma unroll
    for (int j = 0; j < 4; j++) {
      #pragma unroll
      for (int r = 0; r < 4; r++) {
        int rr = row0 + wm + i * 16 + quad * 4 + r;
        int cc = col0 + wn + j * 16 + mrow;
        float v = acc[i][j][r];
        if (bias) v += bias[cc];
        C[(size_t)rr * N + cc] = v;
      }
    }
  }
}

// ---------------- causal depthwise conv(K=4) + SiLU (+ per-head l2norm) ----------------
// Writes [B,H,T,128] layout for the scan.
__global__ __launch_bounds__(256) void conv_silu_kernel(const float* __restrict__ Pre,
                                                        const float* __restrict__ cw,
                                                        float* __restrict__ outp,
                                                        int do_norm) {
  int bt = blockIdx.x;
  int b = bt >> 11, t = bt & (TT - 1);
  int tid = threadIdx.x;
  int ch0 = tid * 8;
  f32x4 wv[8];
  #pragma unroll
  for (int j = 0; j < 8; j++) wv[j] = *(const f32x4*)(cw + (size_t)(ch0 + j) * 4);
  float acc[8] = {0, 0, 0, 0, 0, 0, 0, 0};
  #pragma unroll
  for (int i = 0; i < 4; i++) {
    int tt = t - 3 + i;
    if (tt < 0) continue;
    const float* r = Pre + ((size_t)(b * TT + tt)) * HD + ch0;
    f32x4 a0 = *(const f32x4*)r;
    f32x4 a1 = *(const f32x4*)(r + 4);
    #pragma unroll
    for (int j = 0; j < 4; j++) {
      acc[j]     += a0[j] * wv[j][i];
      acc[4 + j] += a1[j] * wv[4 + j][i];
    }
  }
  float val[8];
  #pragma unroll
  for (int j = 0; j < 8; j++) val[j] = acc[j] / (1.f + expf(-acc[j]));   // SiLU
  if (do_norm) {
    float ss = 0.f;
    #pragma unroll
    for (int j = 0; j < 8; j++) ss += val[j] * val[j];
    ss = reduce16(ss);
    float rs = rsqrtf(ss + 1e-6f);
    #pragma unroll
    for (int j = 0; j < 8; j++) val[j] *= rs;
  }
  int h = tid >> 4, cc = (tid & 15) * 8;
  float* op = outp + (((size_t)(b * HH + h)) * TT + t) * 128 + cc;
  f32x4 o0, o1;
  #pragma unroll
  for (int j = 0; j < 4; j++) { o0[j] = val[j]; o1[j] = val[4 + j]; }
  *(f32x4*)op = o0;
  *(f32x4*)(op + 4) = o1;
}

// ---------------- beta = sigmoid(x @ Wb) -> [B,H,T] layout ----------------
__global__ __launch_bounds__(256) void beta_kernel(const float* __restrict__ x,
                                                   const float* __restrict__ Wb,
                                                   float* __restrict__ beta) {
  __shared__ float xs[2048];
  int bt = blockIdx.x, tid = threadIdx.x;
  int b = bt >> 11, t = bt & (TT - 1);
  const float* row = x + (size_t)bt * DD;
  #pragma unroll
  for (int i = 0; i < 2; i++)
    *(f32x4*)(xs + tid * 8 + i * 4) = *(const f32x4*)(row + tid * 8 + i * 4);
  __syncthreads();
  int h = tid >> 4, seg = tid & 15;
  float p = 0.f;
  for (int j = 0; j < 128; j++) {
    int d = seg * 128 + ((j + seg * 9) & 127);
    p += xs[d] * Wb[(size_t)d * HH + h];
  }
  p = reduce16(p);
  if (seg == 0) beta[((size_t)(b * HH + h)) * TT + t] = 1.f / (1.f + expf(-p));
}

// ---------------- gexp -> [B,H,T,128] layout ----------------
__global__ __launch_bounds__(256) void gexp_kernel(const float* __restrict__ g,
                                                   const float* __restrict__ A_log,
                                                   const float* __restrict__ dt_bias,
                                                   float* __restrict__ ge, int n) {
  int i = blockIdx.x * 256 + threadIdx.x;
  if (i >= n) return;
  int bt = i >> 11, ch = i & (HD - 1);
  int b = bt >> 11, t = bt & (TT - 1);
  int h = ch >> 7, c = ch & 127;
  float gv = g[i] + dt_bias[ch];
  float sp = (gv > 20.f) ? gv : log1pf(expf(gv));
  ge[(((size_t)(b * HH + h)) * TT + t) * 128 + c] = expf(-expf(A_log[h]) * sp);
}

// ---------------- KDA delta-rule scan: 32-lane columns, 2 waves/SIMD ----------------
// Inputs in [B,H,T,128] ([B,H,T] for beta). One block per (b,h) x 16 columns,
// 512 threads = 8 waves; each wave owns 2 columns (32 lanes x 4 elems each).
// Column c0 = rows {0,2} of the wave, c1 = rows {1,3}; 32-lane dot-reduce =
// 4 DPP stages (within 16-row) + v_permlane32_swap (lane^32), all VALU-pipe.
// kg = k*ge precomputed off the recurrence path; u is a single FMA on the path.
// blk mapping: bh = blk&31, colblk = blk>>5 puts all 8 readers of one (b,h)
// stream on the SAME XCD (dispatch d -> XCD d%8), so L2 dedups the 8x re-read.
// v and o alias: block only touches its own 16 columns; writes strictly behind reads.
__global__ __launch_bounds__(512) void scan_kernel(const float* __restrict__ q,
                                                   const float* __restrict__ k,
                                                   const float* v,
                                                   const float* __restrict__ ge,
                                                   const float* __restrict__ beta,
                                                   float* o) {
  __shared__ __align__(16) float kbuf[2][SCH * 128];
  __shared__ __align__(16) float gbuf[2][SCH * 128];
  __shared__ __align__(16) float qbuf[2][SCH * 128];
  __shared__ __align__(16) float vbuf[2][SCH * 16];
  __shared__ __align__(16) float bbuf[TT];

  int blk = blockIdx.x;
  int bh = blk & 31;                        // same-bh blocks share an XCD
  int colblk = blk >> 5;                    // 0..7
  int tid = threadIdx.x;
  int w = tid >> 6, l = tid & 63;
  int half = (l >> 4) & 1;                  // which of the wave's 2 columns
  int i = (l & 15) | ((l & 32) >> 1);       // 0..31 key-group (4 elems each)
  int lcol = w * 2 + half;                  // 0..15 column within block
  int col = colblk * 16 + lcol;             // 0..127 column within head

  const float* kbh = k    + (size_t)bh * TT * 128;
  const float* gbh = ge   + (size_t)bh * TT * 128;
  const float* qbh = q    + (size_t)bh * TT * 128;
  const float* vbh = v    + (size_t)bh * TT * 128;
  const float* bbh = beta + (size_t)bh * TT;
  float* obh = o + (size_t)bh * TT * 128;

  // cooperative staging: waves 0-1 -> k, 2-3 -> g, 4-5 -> q, 6 -> v, 7 -> (beta once)
  auto stage = [&](int cidx, int nb) {
    size_t t0 = (size_t)cidx * SCH;
    if (w < 2) {
      int j0 = w * 4;
      #pragma unroll
      for (int j = 0; j < 4; j++)
        async_ld16(kbh + t0 * 128 + (j0 + j) * 256 + l * 4,
                   (float*)kbuf[nb] + (j0 + j) * 256);
    } else if (w < 4) {
      int j0 = (w - 2) * 4;
      #pragma unroll
      for (int j = 0; j < 4; j++)
        async_ld16(gbh + t0 * 128 + (j0 + j) * 256 + l * 4,
                   (float*)gbuf[nb] + (j0 + j) * 256);
    } else if (w < 6) {
      int j0 = (w - 4) * 4;
      #pragma unroll
      for (int j = 0; j < 4; j++)
        async_ld16(qbh + t0 * 128 + (j0 + j) * 256 + l * 4,
                   (float*)qbuf[nb] + (j0 + j) * 256);
    } else if (w == 6) {
      async_ld16(vbh + (t0 + (size_t)(l >> 2)) * 128 + colblk * 16 + (l & 3) * 4,
                 (float*)vbuf[nb]);
    }
  };

  // stage whole beta sequence (8 KB) once + chunk 0 into buffer 0
  if (w == 7) {
    #pragma unroll
    for (int j = 0; j < 8; j++)
      async_ld16(bbh + j * 256 + l * 4, (float*)bbuf + j * 256);
  }
  stage(0, 0);
  __syncthreads();

  f32x4 sv = {0.f, 0.f, 0.f, 0.f};          // state: 4 key-channels x 1 column
  const float scale = 0.08838834764831845f;  // 128^-0.5

  for (int c = 0; c < TT / SCH; c++) {
    int cb = c & 1, nb = cb ^ 1;
    // async-stage next chunk; latency hidden behind 16 compute steps
    if (c + 1 < TT / SCH) stage(c + 1, nb);

    const float* kc = (const float*)kbuf[cb];
    const float* gc = (const float*)gbuf[cb];
    const float* qc = (const float*)qbuf[cb];
    // register-rotate: load step s+1 while computing step s
    f32x4 k4 = *(const f32x4*)(kc + i * 4);
    f32x4 g4 = *(const f32x4*)(gc + i * 4);
    f32x4 q4 = *(const f32x4*)(qc + i * 4);
    #pragma unroll
    for (int s = 0; s < SCH; s++) {
      f32x4 k4n, g4n, q4n;
      if (s + 1 < SCH) {
        k4n = *(const f32x4*)(kc + (s + 1) * 128 + i * 4);
        g4n = *(const f32x4*)(gc + (s + 1) * 128 + i * 4);
        q4n = *(const f32x4*)(qc + (s + 1) * 128 + i * 4);
      }
      float vt = ((const float*)vbuf[cb])[s * 16 + lcol];
      float bt = bbuf[c * SCH + s];
      // p = k . (S*g) = (k*g) . S_old  -- decay moved off the critical path
      f32x4 kg = k4 * g4;
      f32x4 pp = kg * sv;
      float p = (pp[0] + pp[1]) + (pp[2] + pp[3]);
      p = reduce16(p);
      p = swap32_sum(p);                     // 32-lane column sum, VALU-only
      sv *= g4;                              // decay (parallel with reduce)
      float u = fmaf(-bt, p, vt * bt);       // u = (v - p)*beta, one FMA on path
      sv += k4 * u;
      f32x4 oo = q4 * sv;
      float po = (oo[0] + oo[1]) + (oo[2] + oo[3]);
      po = reduce16(po);
      po = swap32_sum(po);
      if (i == 0) obh[((size_t)c * SCH + s) * 128 + col] = po * scale;
      if (s + 1 < SCH) { k4 = k4n; g4 = g4n; q4 = q4n; }
    }
    __syncthreads();
  }
}

// ---------------- gated RMSNorm -> bf16 (o in [B,H,T,128]) ----------------
__global__ __launch_bounds__(256) void out_norm_kernel(const float* o,
                                                       const float* __restrict__ gate,
                                                       const float* __restrict__ w,
                                                       unsigned short* __restrict__ onb) {
  int bt = blockIdx.x, tid = threadIdx.x;
  int b = bt >> 11, t = bt & (TT - 1);
  int h = tid >> 4, seg = tid & 15;
  size_t obase = (((size_t)(b * HH + h)) * TT + t) * 128 + seg * 8;
  size_t gbase = (size_t)bt * HD + (size_t)h * 128 + seg * 8;
  f32x4 o0 = *(const f32x4*)(o + obase);
  f32x4 o1 = *(const f32x4*)(o + obase + 4);
  float ss = 0.f;
  #pragma unroll
  for (int j = 0; j < 4; j++) ss += o0[j] * o0[j] + o1[j] * o1[j];
  ss = reduce16(ss);
  float rs = rsqrtf(ss * (1.f / 128.f) + 1e-5f);
  u16x4 r0, r1;
  #pragma unroll
  for (int j = 0; j < 4; j++) {
    float gv0 = gate[gbase + j];
    float gv1 = gate[gbase + 4 + j];
    float a0 = o0[j] * rs * w[seg * 8 + j] * (gv0 / (1.f + expf(-gv0)));
    float a1 = o1[j] * rs * w[seg * 8 + 4 + j] * (gv1 / (1.f + expf(-gv1)));
    r0[j] = f2b(a0);
    r1[j] = f2b(a1);
  }
  *(u16x4*)(onb + gbase) = r0;
  *(u16x4*)(onb + gbase + 4) = r1;
}

// ---------------- driver ----------------
extern "C" void kernel_launch(void* const* d_in, const int* in_sizes, int n_in,
                              void* d_out, int out_size, void* d_ws, size_t ws_size,
                              hipStream_t stream) {
  const float* x       = (const float*)d_in[0];
  const float* Wq      = (const float*)d_in[1];
  const float* Wk      = (const float*)d_in[2];
  const float* Wv      = (const float*)d_in[3];
  const float* cq      = (const float*)d_in[4];
  const float* ck      = (const float*)d_in[5];
  const float* cv      = (const float*)d_in[6];
  const float* Wf1     = (const float*)d_in[7];
  const float* Wf2     = (const float*)d_in[8];
  const float* Wb      = (const float*)d_in[9];
  const float* A_log   = (const float*)d_in[10];
  const float* dt_bias = (const float*)d_in[11];
  const float* Wg      = (const float*)d_in[12];
  const float* bg      = (const float*)d_in[13];
  const float* onw     = (const float*)d_in[14];
  const float* Wo      = (const float*)d_in[15];
  float* out = (float*)d_out;

  char* ws = (char*)d_ws;
  unsigned short* WT  = (unsigned short*)(ws);                       //  8 MB rotating W^T
  unsigned short* xb  = (unsigned short*)(ws + ((size_t)8  << 20));  // 16 MB bf16 x
  float* P    = (float*)(ws + ((size_t)24  << 20));                  // 32 MB rotating pre/gate
  float* qb   = (float*)(ws + ((size_t)56  << 20));                  // 32 MB [B,H,T,128]
  float* kb   = (float*)(ws + ((size_t)88  << 20));                  // 32 MB [B,H,T,128]
  float* vb   = (float*)(ws + ((size_t)120 << 20));                  // 32 MB (aliased by o)
  float* geb  = (float*)(ws + ((size_t)152 << 20));                  // 32 MB [B,H,T,128]
  float* betab= (float*)(ws + ((size_t)184 << 20));                  // 256 KB [B,H,T]
  float* f1   = (float*)(ws + ((size_t)185 << 20));                  //   2 MB
  unsigned short* f1b = (unsigned short*)(ws + ((size_t)187 << 20)); //   1 MB
  unsigned short* onb = xb;   // xb dead after gate GEMM
  float* gateb = P;           // P reused as gate buffer
  float* ob    = vb;          // scan output aliases v

  dim3 tb(32, 8);
  dim3 gemm_grid(HD / 128, MM / 128);

  cast_f32_bf16<<<(MM * DD / 4 + 255) / 256, 256, 0, stream>>>(x, xb, MM * DD / 4);

  // q path
  transpose_cast<<<dim3(HD / 32, DD / 32), tb, 0, stream>>>(Wq, WT, DD, HD);
  gemm_bf16<<<gemm_grid, 256, 0, stream>>>(xb, WT, P, nullptr, MM, HD, DD);
  conv_silu_kernel<<<MM, 256, 0, stream>>>(P, cq, qb, 1);
  // k path
  transpose_cast<<<dim3(HD / 32, DD / 32), tb, 0, stream>>>(Wk, WT, DD, HD);
  gemm_bf16<<<gemm_grid, 256, 0, stream>>>(xb, WT, P, nullptr, MM, HD, DD);
  conv_silu_kernel<<<MM, 256, 0, stream>>>(P, ck, kb, 1);
  // v path
  transpose_cast<<<dim3(HD / 32, DD / 32), tb, 0, stream>>>(Wv, WT, DD, HD);
  gemm_bf16<<<gemm_grid, 256, 0, stream>>>(xb, WT, P, nullptr, MM, HD, DD);
  conv_silu_kernel<<<MM, 256, 0, stream>>>(P, cv, vb, 0);

  // beta
  beta_kernel<<<MM, 256, 0, stream>>>(x, Wb, betab);

  // g chain
  transpose_cast<<<dim3(128 / 32, DD / 32), tb, 0, stream>>>(Wf1, WT, DD, 128);
  gemm_bf16<<<dim3(1, MM / 128), 256, 0, stream>>>(xb, WT, f1, nullptr, MM, 128, DD);
  cast_f32_bf16<<<(MM * 128 / 4 + 255) / 256, 256, 0, stream>>>(f1, f1b, MM * 128 / 4);
  transpose_cast<<<dim3(HD / 32, 128 / 32), tb, 0, stream>>>(Wf2, WT, 128, HD);
  gemm_bf16<<<gemm_grid, 256, 0, stream>>>(f1b, WT, P, nullptr, MM, HD, 128);
  gexp_kernel<<<(MM * HD + 255) / 256, 256, 0, stream>>>(P, A_log, dt_bias, geb, MM * HD);

  // gate = x@Wg + bg
  transpose_cast<<<dim3(HD / 32, DD / 32), tb, 0, stream>>>(Wg, WT, DD, HD);
  gemm_bf16<<<gemm_grid, 256, 0, stream>>>(xb, WT, gateb, bg, MM, HD, DD);

  // chunked-pipeline delta-rule scan (512 threads: 2 waves/SIMD latency hiding)
  scan_kernel<<<BB * HH * 8, 512, 0, stream>>>(qb, kb, vb, geb, betab, ob);

  // gated RMSNorm -> bf16
  out_norm_kernel<<<MM, 256, 0, stream>>>(ob, gateb, onw, onb);

  // final projection
  transpose_cast<<<dim3(DD / 32, HD / 32), tb, 0, stream>>>(Wo, WT, HD, DD);
  gemm_bf16<<<dim3(DD / 128, MM / 128), 256, 0, stream>>>(onb, WT, out, nullptr, MM, DD, HD);
}

// Round 3
// 1238.774 us; speedup vs baseline: 1.0539x; 1.0539x over previous
//
#include <hip/hip_runtime.h>
#include <stdint.h>

// Problem constants
#define BB 2
#define TT 2048
#define DD 2048
#define HH 16
#define HD 2048     // H*Dk = H*Dv
#define MM 4096     // B*T
#define SCH 16      // scan chunk steps

typedef float f32x4 __attribute__((ext_vector_type(4)));
typedef __bf16 bf16x8 __attribute__((ext_vector_type(8)));
typedef unsigned short u16x4 __attribute__((ext_vector_type(4)));

__device__ __forceinline__ unsigned short f2b(float f) {
  unsigned int u = __float_as_uint(f);
  u += 0x7FFFu + ((u >> 16) & 1u);   // RNE
  return (unsigned short)(u >> 16);
}

__device__ __forceinline__ void async_ld16(const void* g, void* l) {
  typedef __attribute__((address_space(3))) void as3_t;
  typedef const __attribute__((address_space(1))) void as1_t;
  // NOTE: LDS arg must be WAVE-UNIFORM base; HW adds lane*16 itself.
  __builtin_amdgcn_global_load_lds((as1_t*)(uintptr_t)g,
                                   (as3_t*)(unsigned int)(uintptr_t)l, 16, 0, 0);
}

// ---- DPP 16-lane all-reduce (VALU-pipe; avoids ds_swizzle ~120cyc latency) ----
template <int CTRL>
__device__ __forceinline__ float dpp_add(float x) {
  int y = __builtin_amdgcn_update_dpp(0, __float_as_int(x), CTRL, 0xF, 0xF, false);
  return x + __int_as_float(y);
}
__device__ __forceinline__ float reduce16(float x) {
  x = dpp_add<0xB1>(x);    // quad_perm [1,0,3,2]  (xor 1)
  x = dpp_add<0x4E>(x);    // quad_perm [2,3,0,1]  (xor 2)
  x = dpp_add<0x124>(x);   // row_ror:4
  x = dpp_add<0x128>(x);   // row_ror:8
  return x;                // all 16 lanes hold the row sum
}

// ---------------- cast f32 -> bf16 (vectorized x4) ----------------
__global__ __launch_bounds__(256) void cast_f32_bf16(const float* __restrict__ in,
                                                     unsigned short* __restrict__ out,
                                                     int n4) {
  int i = blockIdx.x * 256 + threadIdx.x;
  if (i >= n4) return;
  f32x4 v = *(const f32x4*)(in + (size_t)i * 4);
  u16x4 r;
  #pragma unroll
  for (int j = 0; j < 4; j++) r[j] = f2b(v[j]);
  *(u16x4*)(out + (size_t)i * 4) = r;
}

// ---------------- transpose + cast: in f32 [R,C] -> out bf16 [C,R] ----------------
__global__ __launch_bounds__(256) void transpose_cast(const float* __restrict__ in,
                                                      unsigned short* __restrict__ out,
                                                      int R, int C) {
  __shared__ float tile[32][33];
  int bx = blockIdx.x * 32, by = blockIdx.y * 32;
  int tx = threadIdx.x, ty = threadIdx.y;
  #pragma unroll
  for (int i = 0; i < 32; i += 8)
    tile[ty + i][tx] = in[(size_t)(by + ty + i) * C + bx + tx];
  __syncthreads();
  #pragma unroll
  for (int i = 0; i < 32; i += 8)
    out[(size_t)(bx + ty + i) * R + by + tx] = f2b(tile[tx][ty + i]);
}

// ---------------- bf16 GEMM: C[M,N] f32 = A[M,K] @ Bt[N,K]^T (+bias) ----------------
__global__ __launch_bounds__(256) void gemm_bf16(const unsigned short* __restrict__ A,
                                                 const unsigned short* __restrict__ Bt,
                                                 float* __restrict__ C,
                                                 const float* __restrict__ bias,
                                                 int M, int N, int K) {
  __shared__ __align__(16) unsigned short As[128 * 32];
  __shared__ __align__(16) unsigned short Bs[128 * 32];
  int tid = threadIdx.x;
  int l = tid & 63, w = tid >> 6;
  int row0 = blockIdx.y * 128, col0 = blockIdx.x * 128;
  int wm = (w >> 1) * 64, wn = (w & 1) * 64;
  const f32x4 fz = {0.f, 0.f, 0.f, 0.f};
  f32x4 acc[4][4];
  #pragma unroll
  for (int i = 0; i < 4; i++)
    #pragma unroll
    for (int j = 0; j < 4; j++) acc[i][j] = fz;

  int srow = l >> 2, skoff = (l & 3) * 8;
  int quad = l >> 4, mrow = l & 15;

  for (int kt = 0; kt < K; kt += 32) {
    #pragma unroll
    for (int i = 0; i < 2; i++) {
      int c = w * 2 + i;
      const unsigned short* gA = A + (size_t)(row0 + c * 16 + srow) * K + kt + skoff;
      const unsigned short* gB = Bt + (size_t)(col0 + c * 16 + srow) * K + kt + skoff;
      async_ld16(gA, As + c * 512);
      async_ld16(gB, Bs + c * 512);
    }
    __syncthreads();
    bf16x8 af[4], bfr[4];
    #pragma unroll
    for (int i = 0; i < 4; i++)
      af[i] = *(const bf16x8*)(As + (wm + i * 16 + mrow) * 32 + quad * 8);
    #pragma unroll
    for (int j = 0; j < 4; j++)
      bfr[j] = *(const bf16x8*)(Bs + (wn + j * 16 + mrow) * 32 + quad * 8);
    #pragma unroll
    for (int i = 0; i < 4; i++)
      #pragma unroll
      for (int j = 0; j < 4; j++)
        acc[i][j] = __builtin_amdgcn_mfma_f32_16x16x32_bf16(af[i], bfr[j], acc[i][j], 0, 0, 0);
    __syncthreads();
  }
  #pragma unroll
  for (int i = 0; i < 4; i++) {
    #pragma unroll
    for (int j = 0; j < 4; j++) {
      #pragma unroll
      for (int r = 0; r < 4; r++) {
        int rr = row0 + wm + i * 16 + quad * 4 + r;
        int cc = col0 + wn + j * 16 + mrow;
        float v = acc[i][j][r];
        if (bias) v += bias[cc];
        C[(size_t)rr * N + cc] = v;
      }
    }
  }
}

// ---------------- causal depthwise conv(K=4) + SiLU (+ per-head l2norm) ----------------
// Writes [B,H,T,128] layout for the scan. post_mul folds the scan's q-scale
// into the l2norm multiplier (free: one extra mul on rs, not per element).
__global__ __launch_bounds__(256) void conv_silu_kernel(const float* __restrict__ Pre,
                                                        const float* __restrict__ cw,
                                                        float* __restrict__ outp,
                                                        int do_norm, float post_mul) {
  int bt = blockIdx.x;
  int b = bt >> 11, t = bt & (TT - 1);
  int tid = threadIdx.x;
  int ch0 = tid * 8;
  f32x4 wv[8];
  #pragma unroll
  for (int j = 0; j < 8; j++) wv[j] = *(const f32x4*)(cw + (size_t)(ch0 + j) * 4);
  float acc[8] = {0, 0, 0, 0, 0, 0, 0, 0};
  #pragma unroll
  for (int i = 0; i < 4; i++) {
    int tt = t - 3 + i;
    if (tt < 0) continue;
    const float* r = Pre + ((size_t)(b * TT + tt)) * HD + ch0;
    f32x4 a0 = *(const f32x4*)r;
    f32x4 a1 = *(const f32x4*)(r + 4);
    #pragma unroll
    for (int j = 0; j < 4; j++) {
      acc[j]     += a0[j] * wv[j][i];
      acc[4 + j] += a1[j] * wv[4 + j][i];
    }
  }
  float val[8];
  #pragma unroll
  for (int j = 0; j < 8; j++) val[j] = acc[j] / (1.f + expf(-acc[j]));   // SiLU
  if (do_norm) {
    float ss = 0.f;
    #pragma unroll
    for (int j = 0; j < 8; j++) ss += val[j] * val[j];
    ss = reduce16(ss);
    float rs = rsqrtf(ss + 1e-6f) * post_mul;
    #pragma unroll
    for (int j = 0; j < 8; j++) val[j] *= rs;
  }
  int h = tid >> 4, cc = (tid & 15) * 8;
  float* op = outp + (((size_t)(b * HH + h)) * TT + t) * 128 + cc;
  f32x4 o0, o1;
  #pragma unroll
  for (int j = 0; j < 4; j++) { o0[j] = val[j]; o1[j] = val[4 + j]; }
  *(f32x4*)op = o0;
  *(f32x4*)(op + 4) = o1;
}

// ---------------- beta = sigmoid(x @ Wb) -> [B,H,T] layout ----------------
__global__ __launch_bounds__(256) void beta_kernel(const float* __restrict__ x,
                                                   const float* __restrict__ Wb,
                                                   float* __restrict__ beta) {
  __shared__ float xs[2048];
  int bt = blockIdx.x, tid = threadIdx.x;
  int b = bt >> 11, t = bt & (TT - 1);
  const float* row = x + (size_t)bt * DD;
  #pragma unroll
  for (int i = 0; i < 2; i++)
    *(f32x4*)(xs + tid * 8 + i * 4) = *(const f32x4*)(row + tid * 8 + i * 4);
  __syncthreads();
  int h = tid >> 4, seg = tid & 15;
  float p = 0.f;
  for (int j = 0; j < 128; j++) {
    int d = seg * 128 + ((j + seg * 9) & 127);
    p += xs[d] * Wb[(size_t)d * HH + h];
  }
  p = reduce16(p);
  if (seg == 0) beta[((size_t)(b * HH + h)) * TT + t] = 1.f / (1.f + expf(-p));
}

// ---------------- gexp -> [B,H,T,128] layout ----------------
__global__ __launch_bounds__(256) void gexp_kernel(const float* __restrict__ g,
                                                   const float* __restrict__ A_log,
                                                   const float* __restrict__ dt_bias,
                                                   float* __restrict__ ge, int n) {
  int i = blockIdx.x * 256 + threadIdx.x;
  if (i >= n) return;
  int bt = i >> 11, ch = i & (HD - 1);
  int b = bt >> 11, t = bt & (TT - 1);
  int h = ch >> 7, c = ch & 127;
  float gv = g[i] + dt_bias[ch];
  float sp = (gv > 20.f) ? gv : log1pf(expf(gv));
  ge[(((size_t)(b * HH + h)) * TT + t) * 128 + c] = expf(-expf(A_log[h]) * sp);
}

// ---------------- KDA delta-rule scan: 16-lane columns + LDS XOR-swizzle ----------------
// Round-0 structure (16 lanes/col, 4 cols/wave, 256 thr) — the 32-lane variant
// inflated instr/col by 1.67x and regressed. This version instead attacks the
// measured costs at 1 wave/SIMD:
//  * 5.03e7 LDS bank conflicts: 8-elem/lane b128 reads at byte i*32 are 4-way
//    bank-quad conflicted (i, i+4, i+8, i+12 collide). Fix: involutive XOR
//    swizzle u^=u>>3 on the 16B-unit index, applied BOTH sides (rule #21):
//    pre-swizzled GLOBAL source in global_load_lds + swizzled read offsets,
//    LDS kept linear. Residual <=2-way = free (m136).
//  * per-step scalar LDS reads (vt,bt) + lgkmcnt waits: hoisted to a per-chunk
//    register preload (v*beta and beta, 16+16 regs).
//  * divergent per-step store: cndmask-keep, 1 store instr per chunk.
//  * q pre-scaled at conv; kg=k*g keeps decay off the recurrence path.
// blk mapping: bh = blk&31 puts all 8 col-blocks of one (b,h) on the same XCD
// (dispatch d -> XCD d%8) so L2 dedups the 8x stream re-read (FETCH 427->66MB).
// v and o alias: block only touches its own 16 columns; writes strictly behind reads.
__global__ __launch_bounds__(256) void scan_kernel(const float* __restrict__ q,
                                                   const float* __restrict__ k,
                                                   const float* v,
                                                   const float* __restrict__ ge,
                                                   const float* __restrict__ beta,
                                                   float* o) {
  __shared__ __align__(16) float kbuf[2][SCH * 128];
  __shared__ __align__(16) float gbuf[2][SCH * 128];
  __shared__ __align__(16) float qbuf[2][SCH * 128];
  __shared__ __align__(16) float vbuf[2][SCH * 16];
  __shared__ __align__(16) float bbuf[TT];

  int blk = blockIdx.x;
  int bh = blk & 31;                        // same-bh blocks share an XCD
  int colblk = blk >> 5;                    // 0..7
  int tid = threadIdx.x;
  int w = tid >> 6, l = tid & 63;
  int grp = l >> 4, i = l & 15;
  int lcol = w * 4 + grp;                   // 0..15: column within block
  int col = colblk * 16 + lcol;             // 0..127: column within head

  // XOR-swizzle (involution) on 16B units within each 512B step-row.
  int u0 = 2 * i, u1 = 2 * i + 1;
  int of0 = (u0 ^ (u0 >> 3)) * 4;           // float offset of lane's first 16B
  int of1 = (u1 ^ (u1 >> 3)) * 4;           // float offset of lane's second 16B
  int su = l & 31;                          // staging: unit within step-row
  int ssw = (su ^ (su >> 3)) * 4;           // pre-swizzled global float offset
  int srow2 = l >> 5;                       // staging: which of 2 steps per instr

  const float* kbh = k    + (size_t)bh * TT * 128;
  const float* gbh = ge   + (size_t)bh * TT * 128;
  const float* qbh = q    + (size_t)bh * TT * 128;
  const float* vbh = v    + (size_t)bh * TT * 128;
  const float* bbh = beta + (size_t)bh * TT;
  float* obh = o + (size_t)bh * TT * 128;

  // stage whole beta sequence (8 KB) once
  #pragma unroll
  for (int j = 0; j < 2; j++) {
    int jj = w * 2 + j;
    async_ld16(bbh + jj * 256 + l * 4, (float*)bbuf + jj * 256);
  }
  // cooperative staging (wave role): source address pre-swizzled, LDS linear
  auto stage = [&](int cidx, int nb) {
    size_t t0 = (size_t)cidx * SCH;
    if (w == 0) {
      #pragma unroll
      for (int j = 0; j < 8; j++)
        async_ld16(kbh + (t0 + j * 2 + srow2) * 128 + ssw,
                   (float*)kbuf[nb] + j * 256);
    } else if (w == 1) {
      #pragma unroll
      for (int j = 0; j < 8; j++)
        async_ld16(gbh + (t0 + j * 2 + srow2) * 128 + ssw,
                   (float*)gbuf[nb] + j * 256);
    } else if (w == 2) {
      #pragma unroll
      for (int j = 0; j < 8; j++)
        async_ld16(qbh + (t0 + j * 2 + srow2) * 128 + ssw,
                   (float*)qbuf[nb] + j * 256);
    } else {
      async_ld16(vbh + (t0 + (size_t)(l >> 2)) * 128 + colblk * 16 + (l & 3) * 4,
                 (float*)vbuf[nb]);
    }
  };
  stage(0, 0);
  __syncthreads();

  f32x4 s0 = {0.f, 0.f, 0.f, 0.f}, s1 = {0.f, 0.f, 0.f, 0.f};
  float okeep = 0.f;

  for (int c = 0; c < TT / SCH; c++) {
    int cb = c & 1, nb = cb ^ 1;
    // async-stage next chunk; latency hidden behind 16 compute steps
    if (c + 1 < TT / SCH) stage(c + 1, nb);

    const float* kc = (const float*)kbuf[cb];
    const float* gc = (const float*)gbuf[cb];
    const float* qc = (const float*)qbuf[cb];
    // per-chunk preload: v*beta and beta into registers (waits off step loop)
    float vbt[SCH], btp[SCH];
    #pragma unroll
    for (int s = 0; s < SCH; s++) {
      float vv = ((const float*)vbuf[cb])[s * 16 + lcol];  // 16-lane broadcast
      float bb = bbuf[c * SCH + s];                        // uniform
      btp[s] = bb;
      vbt[s] = vv * bb;
    }
    // register-rotate: load step s+1 while computing step s (swizzled offsets)
    f32x4 k0 = *(const f32x4*)(kc + of0), k1 = *(const f32x4*)(kc + of1);
    f32x4 g0 = *(const f32x4*)(gc + of0), g1 = *(const f32x4*)(gc + of1);
    f32x4 q0 = *(const f32x4*)(qc + of0), q1 = *(const f32x4*)(qc + of1);
    #pragma unroll
    for (int s = 0; s < SCH; s++) {
      f32x4 k0n, k1n, g0n, g1n, q0n, q1n;
      if (s + 1 < SCH) {
        const float* kp = kc + (s + 1) * 128;
        const float* gp = gc + (s + 1) * 128;
        const float* qp = qc + (s + 1) * 128;
        k0n = *(const f32x4*)(kp + of0); k1n = *(const f32x4*)(kp + of1);
        g0n = *(const f32x4*)(gp + of0); g1n = *(const f32x4*)(gp + of1);
        q0n = *(const f32x4*)(qp + of0); q1n = *(const f32x4*)(qp + of1);
      }
      // p = k . (S*g) = (k*g) . S_old  -- decay off the critical path
      f32x4 kg0 = k0 * g0, kg1 = k1 * g1;
      f32x4 pp = kg0 * s0 + kg1 * s1;
      float p = (pp[0] + pp[1]) + (pp[2] + pp[3]);
      p = reduce16(p);                       // DPP butterfly on the path
      s0 *= g0; s1 *= g1;                    // decay (overlaps the reduce)
      float u = fmaf(-btp[s], p, vbt[s]);    // u = (v - p)*beta, one FMA on path
      s0 += k0 * u; s1 += k1 * u;
      f32x4 oo = q0 * s0 + q1 * s1;          // q pre-scaled by 128^-0.5
      float po = (oo[0] + oo[1]) + (oo[2] + oo[3]);
      po = reduce16(po);                     // off the recurrence path
      okeep = (i == s) ? po : okeep;         // cndmask, no divergence
      if (s + 1 < SCH) {
        k0 = k0n; k1 = k1n; g0 = g0n; g1 = g1n; q0 = q0n; q1 = q1n;
      }
    }
    // one store per chunk: lane i holds step i's output for its column
    obh[((size_t)c * SCH + i) * 128 + col] = okeep;
    __syncthreads();
  }
}

// ---------------- gated RMSNorm -> bf16 (o in [B,H,T,128]) ----------------
__global__ __launch_bounds__(256) void out_norm_kernel(const float* o,
                                                       const float* __restrict__ gate,
                                                       const float* __restrict__ w,
                                                       unsigned short* __restrict__ onb) {
  int bt = blockIdx.x, tid = threadIdx.x;
  int b = bt >> 11, t = bt & (TT - 1);
  int h = tid >> 4, seg = tid & 15;
  size_t obase = (((size_t)(b * HH + h)) * TT + t) * 128 + seg * 8;
  size_t gbase = (size_t)bt * HD + (size_t)h * 128 + seg * 8;
  f32x4 o0 = *(const f32x4*)(o + obase);
  f32x4 o1 = *(const f32x4*)(o + obase + 4);
  float ss = 0.f;
  #pragma unroll
  for (int j = 0; j < 4; j++) ss += o0[j] * o0[j] + o1[j] * o1[j];
  ss = reduce16(ss);
  float rs = rsqrtf(ss * (1.f / 128.f) + 1e-5f);
  u16x4 r0, r1;
  #pragma unroll
  for (int j = 0; j < 4; j++) {
    float gv0 = gate[gbase + j];
    float gv1 = gate[gbase + 4 + j];
    float a0 = o0[j] * rs * w[seg * 8 + j] * (gv0 / (1.f + expf(-gv0)));
    float a1 = o1[j] * rs * w[seg * 8 + 4 + j] * (gv1 / (1.f + expf(-gv1)));
    r0[j] = f2b(a0);
    r1[j] = f2b(a1);
  }
  *(u16x4*)(onb + gbase) = r0;
  *(u16x4*)(onb + gbase + 4) = r1;
}

// ---------------- driver ----------------
extern "C" void kernel_launch(void* const* d_in, const int* in_sizes, int n_in,
                              void* d_out, int out_size, void* d_ws, size_t ws_size,
                              hipStream_t stream) {
  const float* x       = (const float*)d_in[0];
  const float* Wq      = (const float*)d_in[1];
  const float* Wk      = (const float*)d_in[2];
  const float* Wv      = (const float*)d_in[3];
  const float* cq      = (const float*)d_in[4];
  const float* ck      = (const float*)d_in[5];
  const float* cv      = (const float*)d_in[6];
  const float* Wf1     = (const float*)d_in[7];
  const float* Wf2     = (const float*)d_in[8];
  const float* Wb      = (const float*)d_in[9];
  const float* A_log   = (const float*)d_in[10];
  const float* dt_bias = (const float*)d_in[11];
  const float* Wg      = (const float*)d_in[12];
  const float* bg      = (const float*)d_in[13];
  const float* onw     = (const float*)d_in[14];
  const float* Wo      = (const float*)d_in[15];
  float* out = (float*)d_out;

  char* ws = (char*)d_ws;
  unsigned short* WT  = (unsigned short*)(ws);                       //  8 MB rotating W^T
  unsigned short* xb  = (unsigned short*)(ws + ((size_t)8  << 20));  // 16 MB bf16 x
  float* P    = (float*)(ws + ((size_t)24  << 20));                  // 32 MB rotating pre/gate
  float* qb   = (float*)(ws + ((size_t)56  << 20));                  // 32 MB [B,H,T,128]
  float* kb   = (float*)(ws + ((size_t)88  << 20));                  // 32 MB [B,H,T,128]
  float* vb   = (float*)(ws + ((size_t)120 << 20));                  // 32 MB (aliased by o)
  float* geb  = (float*)(ws + ((size_t)152 << 20));                  // 32 MB [B,H,T,128]
  float* betab= (float*)(ws + ((size_t)184 << 20));                  // 256 KB [B,H,T]
  float* f1   = (float*)(ws + ((size_t)185 << 20));                  //   2 MB
  unsigned short* f1b = (unsigned short*)(ws + ((size_t)187 << 20)); //   1 MB
  unsigned short* onb = xb;   // xb dead after gate GEMM
  float* gateb = P;           // P reused as gate buffer
  float* ob    = vb;          // scan output aliases v

  dim3 tb(32, 8);
  dim3 gemm_grid(HD / 128, MM / 128);

  cast_f32_bf16<<<(MM * DD / 4 + 255) / 256, 256, 0, stream>>>(x, xb, MM * DD / 4);

  // q path (scan scale 128^-0.5 folded into l2norm)
  transpose_cast<<<dim3(HD / 32, DD / 32), tb, 0, stream>>>(Wq, WT, DD, HD);
  gemm_bf16<<<gemm_grid, 256, 0, stream>>>(xb, WT, P, nullptr, MM, HD, DD);
  conv_silu_kernel<<<MM, 256, 0, stream>>>(P, cq, qb, 1, 0.08838834764831845f);
  // k path
  transpose_cast<<<dim3(HD / 32, DD / 32), tb, 0, stream>>>(Wk, WT, DD, HD);
  gemm_bf16<<<gemm_grid, 256, 0, stream>>>(xb, WT, P, nullptr, MM, HD, DD);
  conv_silu_kernel<<<MM, 256, 0, stream>>>(P, ck, kb, 1, 1.0f);
  // v path
  transpose_cast<<<dim3(HD / 32, DD / 32), tb, 0, stream>>>(Wv, WT, DD, HD);
  gemm_bf16<<<gemm_grid, 256, 0, stream>>>(xb, WT, P, nullptr, MM, HD, DD);
  conv_silu_kernel<<<MM, 256, 0, stream>>>(P, cv, vb, 0, 1.0f);

  // beta
  beta_kernel<<<MM, 256, 0, stream>>>(x, Wb, betab);

  // g chain
  transpose_cast<<<dim3(128 / 32, DD / 32), tb, 0, stream>>>(Wf1, WT, DD, 128);
  gemm_bf16<<<dim3(1, MM / 128), 256, 0, stream>>>(xb, WT, f1, nullptr, MM, 128, DD);
  cast_f32_bf16<<<(MM * 128 / 4 + 255) / 256, 256, 0, stream>>>(f1, f1b, MM * 128 / 4);
  transpose_cast<<<dim3(HD / 32, 128 / 32), tb, 0, stream>>>(Wf2, WT, 128, HD);
  gemm_bf16<<<gemm_grid, 256, 0, stream>>>(f1b, WT, P, nullptr, MM, HD, 128);
  gexp_kernel<<<(MM * HD + 255) / 256, 256, 0, stream>>>(P, A_log, dt_bias, geb, MM * HD);

  // gate = x@Wg + bg
  transpose_cast<<<dim3(HD / 32, DD / 32), tb, 0, stream>>>(Wg, WT, DD, HD);
  gemm_bf16<<<gemm_grid, 256, 0, stream>>>(xb, WT, gateb, bg, MM, HD, DD);

  // chunked-pipeline delta-rule scan (16-lane cols, swizzled LDS)
  scan_kernel<<<BB * HH * 8, 256, 0, stream>>>(qb, kb, vb, geb, betab, ob);

  // gated RMSNorm -> bf16
  out_norm_kernel<<<MM, 256, 0, stream>>>(ob, gateb, onw, onb);

  // final projection
  transpose_cast<<<dim3(DD / 32, HD / 32), tb, 0, stream>>>(Wo, WT, HD, DD);
  gemm_bf16<<<dim3(DD / 128, MM / 128), 256, 0, stream>>>(onb, WT, out, nullptr, MM, DD, HD);
}

// Round 4
// 1207.576 us; speedup vs baseline: 1.0812x; 1.0258x over previous
//
#include <hip/hip_runtime.h>
#include <stdint.h>

// Problem constants
#define BB 2
#define TT 2048
#define DD 2048
#define HH 16
#define HD 2048     // H*Dk = H*Dv
#define MM 4096     // B*T
#define SCH 16      // scan chunk steps

typedef float f32x4 __attribute__((ext_vector_type(4)));
typedef __bf16 bf16x8 __attribute__((ext_vector_type(8)));
typedef unsigned short u16x4 __attribute__((ext_vector_type(4)));

__device__ __forceinline__ unsigned short f2b(float f) {
  unsigned int u = __float_as_uint(f);
  u += 0x7FFFu + ((u >> 16) & 1u);   // RNE
  return (unsigned short)(u >> 16);
}

__device__ __forceinline__ void async_ld16(const void* g, void* l) {
  typedef __attribute__((address_space(3))) void as3_t;
  typedef const __attribute__((address_space(1))) void as1_t;
  // NOTE: LDS arg must be WAVE-UNIFORM base; HW adds lane*16 itself.
  __builtin_amdgcn_global_load_lds((as1_t*)(uintptr_t)g,
                                   (as3_t*)(unsigned int)(uintptr_t)l, 16, 0, 0);
}

// ---- DPP 16-lane all-reduce (VALU-pipe; avoids ds_swizzle ~120cyc latency) ----
template <int CTRL>
__device__ __forceinline__ float dpp_add(float x) {
  int y = __builtin_amdgcn_update_dpp(0, __float_as_int(x), CTRL, 0xF, 0xF, false);
  return x + __int_as_float(y);
}
__device__ __forceinline__ float reduce16(float x) {
  x = dpp_add<0xB1>(x);    // quad_perm [1,0,3,2]  (xor 1)
  x = dpp_add<0x4E>(x);    // quad_perm [2,3,0,1]  (xor 2)
  x = dpp_add<0x124>(x);   // row_ror:4
  x = dpp_add<0x128>(x);   // row_ror:8
  return x;                // all 16 lanes hold the row sum
}

// ---------------- cast f32 -> bf16 (vectorized x4) ----------------
__global__ __launch_bounds__(256) void cast_f32_bf16(const float* __restrict__ in,
                                                     unsigned short* __restrict__ out,
                                                     int n4) {
  int i = blockIdx.x * 256 + threadIdx.x;
  if (i >= n4) return;
  f32x4 v = *(const f32x4*)(in + (size_t)i * 4);
  u16x4 r;
  #pragma unroll
  for (int j = 0; j < 4; j++) r[j] = f2b(v[j]);
  *(u16x4*)(out + (size_t)i * 4) = r;
}

// ---------------- transpose + cast: in f32 [R,C] -> out bf16 [C,R] ----------------
__global__ __launch_bounds__(256) void transpose_cast(const float* __restrict__ in,
                                                      unsigned short* __restrict__ out,
                                                      int R, int C) {
  __shared__ float tile[32][33];
  int bx = blockIdx.x * 32, by = blockIdx.y * 32;
  int tx = threadIdx.x, ty = threadIdx.y;
  #pragma unroll
  for (int i = 0; i < 32; i += 8)
    tile[ty + i][tx] = in[(size_t)(by + ty + i) * C + bx + tx];
  __syncthreads();
  #pragma unroll
  for (int i = 0; i < 32; i += 8)
    out[(size_t)(bx + ty + i) * R + by + tx] = f2b(tile[tx][ty + i]);
}

// ---------------- bf16 GEMM: C[M,N] f32 = A[M,K] @ Bt[N,K]^T (+bias) ----------------
__global__ __launch_bounds__(256) void gemm_bf16(const unsigned short* __restrict__ A,
                                                 const unsigned short* __restrict__ Bt,
                                                 float* __restrict__ C,
                                                 const float* __restrict__ bias,
                                                 int M, int N, int K) {
  __shared__ __align__(16) unsigned short As[128 * 32];
  __shared__ __align__(16) unsigned short Bs[128 * 32];
  int tid = threadIdx.x;
  int l = tid & 63, w = tid >> 6;
  int row0 = blockIdx.y * 128, col0 = blockIdx.x * 128;
  int wm = (w >> 1) * 64, wn = (w & 1) * 64;
  const f32x4 fz = {0.f, 0.f, 0.f, 0.f};
  f32x4 acc[4][4];
  #pragma unroll
  for (int i = 0; i < 4; i++)
    #pragma unroll
    for (int j = 0; j < 4; j++) acc[i][j] = fz;

  int srow = l >> 2, skoff = (l & 3) * 8;
  int quad = l >> 4, mrow = l & 15;

  for (int kt = 0; kt < K; kt += 32) {
    #pragma unroll
    for (int i = 0; i < 2; i++) {
      int c = w * 2 + i;
      const unsigned short* gA = A + (size_t)(row0 + c * 16 + srow) * K + kt + skoff;
      const unsigned short* gB = Bt + (size_t)(col0 + c * 16 + srow) * K + kt + skoff;
      async_ld16(gA, As + c * 512);
      async_ld16(gB, Bs + c * 512);
    }
    __syncthreads();
    bf16x8 af[4], bfr[4];
    #pragma unroll
    for (int i = 0; i < 4; i++)
      af[i] = *(const bf16x8*)(As + (wm + i * 16 + mrow) * 32 + quad * 8);
    #pragma unroll
    for (int j = 0; j < 4; j++)
      bfr[j] = *(const bf16x8*)(Bs + (wn + j * 16 + mrow) * 32 + quad * 8);
    #pragma unroll
    for (int i = 0; i < 4; i++)
      #pragma unroll
      for (int j = 0; j < 4; j++)
        acc[i][j] = __builtin_amdgcn_mfma_f32_16x16x32_bf16(af[i], bfr[j], acc[i][j], 0, 0, 0);
    __syncthreads();
  }
  #pragma unroll
  for (int i = 0; i < 4; i++) {
    #pragma unroll
    for (int j = 0; j < 4; j++) {
      #pragma unroll
      for (int r = 0; r < 4; r++) {
        int rr = row0 + wm + i * 16 + quad * 4 + r;
        int cc = col0 + wn + j * 16 + mrow;
        float v = acc[i][j][r];
        if (bias) v += bias[cc];
        C[(size_t)rr * N + cc] = v;
      }
    }
  }
}

// ---------------- causal depthwise conv(K=4) + SiLU (+ per-head l2norm) ----------------
// Writes [B,H,T,128] layout for the scan. post_mul folds the scan's q-scale
// into the l2norm multiplier (free: one extra mul on rs, not per element).
__global__ __launch_bounds__(256) void conv_silu_kernel(const float* __restrict__ Pre,
                                                        const float* __restrict__ cw,
                                                        float* __restrict__ outp,
                                                        int do_norm, float post_mul) {
  int bt = blockIdx.x;
  int b = bt >> 11, t = bt & (TT - 1);
  int tid = threadIdx.x;
  int ch0 = tid * 8;
  f32x4 wv[8];
  #pragma unroll
  for (int j = 0; j < 8; j++) wv[j] = *(const f32x4*)(cw + (size_t)(ch0 + j) * 4);
  float acc[8] = {0, 0, 0, 0, 0, 0, 0, 0};
  #pragma unroll
  for (int i = 0; i < 4; i++) {
    int tt = t - 3 + i;
    if (tt < 0) continue;
    const float* r = Pre + ((size_t)(b * TT + tt)) * HD + ch0;
    f32x4 a0 = *(const f32x4*)r;
    f32x4 a1 = *(const f32x4*)(r + 4);
    #pragma unroll
    for (int j = 0; j < 4; j++) {
      acc[j]     += a0[j] * wv[j][i];
      acc[4 + j] += a1[j] * wv[4 + j][i];
    }
  }
  float val[8];
  #pragma unroll
  for (int j = 0; j < 8; j++) val[j] = acc[j] / (1.f + expf(-acc[j]));   // SiLU
  if (do_norm) {
    float ss = 0.f;
    #pragma unroll
    for (int j = 0; j < 8; j++) ss += val[j] * val[j];
    ss = reduce16(ss);
    float rs = rsqrtf(ss + 1e-6f) * post_mul;
    #pragma unroll
    for (int j = 0; j < 8; j++) val[j] *= rs;
  }
  int h = tid >> 4, cc = (tid & 15) * 8;
  float* op = outp + (((size_t)(b * HH + h)) * TT + t) * 128 + cc;
  f32x4 o0, o1;
  #pragma unroll
  for (int j = 0; j < 4; j++) { o0[j] = val[j]; o1[j] = val[4 + j]; }
  *(f32x4*)op = o0;
  *(f32x4*)(op + 4) = o1;
}

// ---------------- beta = sigmoid(x @ Wb) -> [B,H,T] layout ----------------
__global__ __launch_bounds__(256) void beta_kernel(const float* __restrict__ x,
                                                   const float* __restrict__ Wb,
                                                   float* __restrict__ beta) {
  __shared__ float xs[2048];
  int bt = blockIdx.x, tid = threadIdx.x;
  int b = bt >> 11, t = bt & (TT - 1);
  const float* row = x + (size_t)bt * DD;
  #pragma unroll
  for (int i = 0; i < 2; i++)
    *(f32x4*)(xs + tid * 8 + i * 4) = *(const f32x4*)(row + tid * 8 + i * 4);
  __syncthreads();
  int h = tid >> 4, seg = tid & 15;
  float p = 0.f;
  for (int j = 0; j < 128; j++) {
    int d = seg * 128 + ((j + seg * 9) & 127);
    p += xs[d] * Wb[(size_t)d * HH + h];
  }
  p = reduce16(p);
  if (seg == 0) beta[((size_t)(b * HH + h)) * TT + t] = 1.f / (1.f + expf(-p));
}

// ---------------- gexp -> [B,H,T,128] layout ----------------
__global__ __launch_bounds__(256) void gexp_kernel(const float* __restrict__ g,
                                                   const float* __restrict__ A_log,
                                                   const float* __restrict__ dt_bias,
                                                   float* __restrict__ ge, int n) {
  int i = blockIdx.x * 256 + threadIdx.x;
  if (i >= n) return;
  int bt = i >> 11, ch = i & (HD - 1);
  int b = bt >> 11, t = bt & (TT - 1);
  int h = ch >> 7, c = ch & 127;
  float gv = g[i] + dt_bias[ch];
  float sp = (gv > 20.f) ? gv : log1pf(expf(gv));
  ge[(((size_t)(b * HH + h)) * TT + t) * 128 + c] = expf(-expf(A_log[h]) * sp);
}

// ---------------- KDA delta-rule scan: 16-lane columns, parity-split reads ----------------
// Conflict model (cross-round evidence): a wave64 ds_read_b128 presenting 16
// distinct 16B units at 4-fold lane multiplicity costs ~16 extra LDS cycles
// (r0/r3: 5.03e7 conflicts, invariant under unit permutation/XOR swizzle);
// 32 distinct units at 2-fold multiplicity costs 0 (r2 measured). Fix at zero
// instruction cost: PARITY-SPLIT — column-groups 0,2 read (even,odd) units,
// groups 1,3 read (odd,even). Dot products are order-invariant and k/g/q/S
// all share of0/of1, so lane channel-ownership {8i..8i+7} is unchanged.
//  * per-chunk register preload of v*beta,beta (waits off the step loop)
//  * cndmask-keep store: one global store per chunk
//  * q pre-scaled at conv; kg=k*g keeps decay off the recurrence path
// blk mapping: bh = blk&31 puts all 8 col-blocks of one (b,h) on the same XCD
// (dispatch d -> XCD d%8) so L2 dedups the 8x stream re-read (FETCH 427->66MB).
// v and o alias: block only touches its own 16 columns; writes strictly behind reads.
__global__ __launch_bounds__(256) void scan_kernel(const float* __restrict__ q,
                                                   const float* __restrict__ k,
                                                   const float* v,
                                                   const float* __restrict__ ge,
                                                   const float* __restrict__ beta,
                                                   float* o) {
  __shared__ __align__(16) float kbuf[2][SCH * 128];
  __shared__ __align__(16) float gbuf[2][SCH * 128];
  __shared__ __align__(16) float qbuf[2][SCH * 128];
  __shared__ __align__(16) float vbuf[2][SCH * 16];
  __shared__ __align__(16) float bbuf[TT];

  int blk = blockIdx.x;
  int bh = blk & 31;                        // same-bh blocks share an XCD
  int colblk = blk >> 5;                    // 0..7
  int tid = threadIdx.x;
  int w = tid >> 6, l = tid & 63;
  int grp = l >> 4, i = l & 15;
  int lcol = w * 4 + grp;                   // 0..15: column within block
  int col = colblk * 16 + lcol;             // 0..127: column within head

  // Parity-split 16B-unit offsets: groups 0,2 -> (even,odd); 1,3 -> (odd,even).
  // Wave-wide: each read presents 32 DISTINCT units at 2-fold multiplicity.
  int par = grp & 1;
  int of0 = (2 * i + par) * 4;              // float offset of lane's first 16B
  int of1 = (2 * i + (1 - par)) * 4;        // float offset of lane's second 16B

  const float* kbh = k    + (size_t)bh * TT * 128;
  const float* gbh = ge   + (size_t)bh * TT * 128;
  const float* qbh = q    + (size_t)bh * TT * 128;
  const float* vbh = v    + (size_t)bh * TT * 128;
  const float* bbh = beta + (size_t)bh * TT;
  float* obh = o + (size_t)bh * TT * 128;

  // stage whole beta sequence (8 KB) once
  #pragma unroll
  for (int j = 0; j < 2; j++) {
    int jj = w * 2 + j;
    async_ld16(bbh + jj * 256 + l * 4, (float*)bbuf + jj * 256);
  }
  // cooperative staging (wave role), contiguous source + linear LDS
  auto stage = [&](int cidx, int nb) {
    size_t t0 = (size_t)cidx * SCH;
    if (w == 0) {
      #pragma unroll
      for (int j = 0; j < 8; j++)
        async_ld16(kbh + t0 * 128 + j * 256 + l * 4, (float*)kbuf[nb] + j * 256);
    } else if (w == 1) {
      #pragma unroll
      for (int j = 0; j < 8; j++)
        async_ld16(gbh + t0 * 128 + j * 256 + l * 4, (float*)gbuf[nb] + j * 256);
    } else if (w == 2) {
      #pragma unroll
      for (int j = 0; j < 8; j++)
        async_ld16(qbh + t0 * 128 + j * 256 + l * 4, (float*)qbuf[nb] + j * 256);
    } else {
      async_ld16(vbh + (t0 + (size_t)(l >> 2)) * 128 + colblk * 16 + (l & 3) * 4,
                 (float*)vbuf[nb]);
    }
  };
  stage(0, 0);
  __syncthreads();

  f32x4 s0 = {0.f, 0.f, 0.f, 0.f}, s1 = {0.f, 0.f, 0.f, 0.f};
  float okeep = 0.f;

  for (int c = 0; c < TT / SCH; c++) {
    int cb = c & 1, nb = cb ^ 1;
    // async-stage next chunk; latency hidden behind 16 compute steps
    if (c + 1 < TT / SCH) stage(c + 1, nb);

    const float* kc = (const float*)kbuf[cb];
    const float* gc = (const float*)gbuf[cb];
    const float* qc = (const float*)qbuf[cb];
    // per-chunk preload: v*beta and beta into registers (waits off step loop)
    float vbt[SCH], btp[SCH];
    #pragma unroll
    for (int s = 0; s < SCH; s++) {
      float vv = ((const float*)vbuf[cb])[s * 16 + lcol];  // 16-lane broadcast
      float bb = bbuf[c * SCH + s];                        // uniform
      btp[s] = bb;
      vbt[s] = vv * bb;
    }
    // register-rotate: load step s+1 while computing step s (parity offsets)
    f32x4 k0 = *(const f32x4*)(kc + of0), k1 = *(const f32x4*)(kc + of1);
    f32x4 g0 = *(const f32x4*)(gc + of0), g1 = *(const f32x4*)(gc + of1);
    f32x4 q0 = *(const f32x4*)(qc + of0), q1 = *(const f32x4*)(qc + of1);
    #pragma unroll
    for (int s = 0; s < SCH; s++) {
      f32x4 k0n, k1n, g0n, g1n, q0n, q1n;
      if (s + 1 < SCH) {
        const float* kp = kc + (s + 1) * 128;
        const float* gp = gc + (s + 1) * 128;
        const float* qp = qc + (s + 1) * 128;
        k0n = *(const f32x4*)(kp + of0); k1n = *(const f32x4*)(kp + of1);
        g0n = *(const f32x4*)(gp + of0); g1n = *(const f32x4*)(gp + of1);
        q0n = *(const f32x4*)(qp + of0); q1n = *(const f32x4*)(qp + of1);
      }
      // p = k . (S*g) = (k*g) . S_old  -- decay off the critical path
      f32x4 kg0 = k0 * g0, kg1 = k1 * g1;
      f32x4 pp = kg0 * s0 + kg1 * s1;
      float p = (pp[0] + pp[1]) + (pp[2] + pp[3]);
      p = reduce16(p);                       // DPP butterfly on the path
      s0 *= g0; s1 *= g1;                    // decay (overlaps the reduce)
      float u = fmaf(-btp[s], p, vbt[s]);    // u = (v - p)*beta, one FMA on path
      s0 += k0 * u; s1 += k1 * u;
      f32x4 oo = q0 * s0 + q1 * s1;          // q pre-scaled by 128^-0.5
      float po = (oo[0] + oo[1]) + (oo[2] + oo[3]);
      po = reduce16(po);                     // off the recurrence path
      okeep = (i == s) ? po : okeep;         // cndmask, no divergence
      if (s + 1 < SCH) {
        k0 = k0n; k1 = k1n; g0 = g0n; g1 = g1n; q0 = q0n; q1 = q1n;
      }
    }
    // one store per chunk: lane i holds step i's output for its column
    obh[((size_t)c * SCH + i) * 128 + col] = okeep;
    __syncthreads();
  }
}

// ---------------- gated RMSNorm -> bf16 (o in [B,H,T,128]) ----------------
__global__ __launch_bounds__(256) void out_norm_kernel(const float* o,
                                                       const float* __restrict__ gate,
                                                       const float* __restrict__ w,
                                                       unsigned short* __restrict__ onb) {
  int bt = blockIdx.x, tid = threadIdx.x;
  int b = bt >> 11, t = bt & (TT - 1);
  int h = tid >> 4, seg = tid & 15;
  size_t obase = (((size_t)(b * HH + h)) * TT + t) * 128 + seg * 8;
  size_t gbase = (size_t)bt * HD + (size_t)h * 128 + seg * 8;
  f32x4 o0 = *(const f32x4*)(o + obase);
  f32x4 o1 = *(const f32x4*)(o + obase + 4);
  float ss = 0.f;
  #pragma unroll
  for (int j = 0; j < 4; j++) ss += o0[j] * o0[j] + o1[j] * o1[j];
  ss = reduce16(ss);
  float rs = rsqrtf(ss * (1.f / 128.f) + 1e-5f);
  u16x4 r0, r1;
  #pragma unroll
  for (int j = 0; j < 4; j++) {
    float gv0 = gate[gbase + j];
    float gv1 = gate[gbase + 4 + j];
    float a0 = o0[j] * rs * w[seg * 8 + j] * (gv0 / (1.f + expf(-gv0)));
    float a1 = o1[j] * rs * w[seg * 8 + 4 + j] * (gv1 / (1.f + expf(-gv1)));
    r0[j] = f2b(a0);
    r1[j] = f2b(a1);
  }
  *(u16x4*)(onb + gbase) = r0;
  *(u16x4*)(onb + gbase + 4) = r1;
}

// ---------------- driver ----------------
extern "C" void kernel_launch(void* const* d_in, const int* in_sizes, int n_in,
                              void* d_out, int out_size, void* d_ws, size_t ws_size,
                              hipStream_t stream) {
  const float* x       = (const float*)d_in[0];
  const float* Wq      = (const float*)d_in[1];
  const float* Wk      = (const float*)d_in[2];
  const float* Wv      = (const float*)d_in[3];
  const float* cq      = (const float*)d_in[4];
  const float* ck      = (const float*)d_in[5];
  const float* cv      = (const float*)d_in[6];
  const float* Wf1     = (const float*)d_in[7];
  const float* Wf2     = (const float*)d_in[8];
  const float* Wb      = (const float*)d_in[9];
  const float* A_log   = (const float*)d_in[10];
  const float* dt_bias = (const float*)d_in[11];
  const float* Wg      = (const float*)d_in[12];
  const float* bg      = (const float*)d_in[13];
  const float* onw     = (const float*)d_in[14];
  const float* Wo      = (const float*)d_in[15];
  float* out = (float*)d_out;

  char* ws = (char*)d_ws;
  unsigned short* WT  = (unsigned short*)(ws);                       //  8 MB rotating W^T
  unsigned short* xb  = (unsigned short*)(ws + ((size_t)8  << 20));  // 16 MB bf16 x
  float* P    = (float*)(ws + ((size_t)24  << 20));                  // 32 MB rotating pre/gate
  float* qb   = (float*)(ws + ((size_t)56  << 20));                  // 32 MB [B,H,T,128]
  float* kb   = (float*)(ws + ((size_t)88  << 20));                  // 32 MB [B,H,T,128]
  float* vb   = (float*)(ws + ((size_t)120 << 20));                  // 32 MB (aliased by o)
  float* geb  = (float*)(ws + ((size_t)152 << 20));                  // 32 MB [B,H,T,128]
  float* betab= (float*)(ws + ((size_t)184 << 20));                  // 256 KB [B,H,T]
  float* f1   = (float*)(ws + ((size_t)185 << 20));                  //   2 MB
  unsigned short* f1b = (unsigned short*)(ws + ((size_t)187 << 20)); //   1 MB
  unsigned short* onb = xb;   // xb dead after gate GEMM
  float* gateb = P;           // P reused as gate buffer
  float* ob    = vb;          // scan output aliases v

  dim3 tb(32, 8);
  dim3 gemm_grid(HD / 128, MM / 128);

  cast_f32_bf16<<<(MM * DD / 4 + 255) / 256, 256, 0, stream>>>(x, xb, MM * DD / 4);

  // q path (scan scale 128^-0.5 folded into l2norm)
  transpose_cast<<<dim3(HD / 32, DD / 32), tb, 0, stream>>>(Wq, WT, DD, HD);
  gemm_bf16<<<gemm_grid, 256, 0, stream>>>(xb, WT, P, nullptr, MM, HD, DD);
  conv_silu_kernel<<<MM, 256, 0, stream>>>(P, cq, qb, 1, 0.08838834764831845f);
  // k path
  transpose_cast<<<dim3(HD / 32, DD / 32), tb, 0, stream>>>(Wk, WT, DD, HD);
  gemm_bf16<<<gemm_grid, 256, 0, stream>>>(xb, WT, P, nullptr, MM, HD, DD);
  conv_silu_kernel<<<MM, 256, 0, stream>>>(P, ck, kb, 1, 1.0f);
  // v path
  transpose_cast<<<dim3(HD / 32, DD / 32), tb, 0, stream>>>(Wv, WT, DD, HD);
  gemm_bf16<<<gemm_grid, 256, 0, stream>>>(xb, WT, P, nullptr, MM, HD, DD);
  conv_silu_kernel<<<MM, 256, 0, stream>>>(P, cv, vb, 0, 1.0f);

  // beta
  beta_kernel<<<MM, 256, 0, stream>>>(x, Wb, betab);

  // g chain
  transpose_cast<<<dim3(128 / 32, DD / 32), tb, 0, stream>>>(Wf1, WT, DD, 128);
  gemm_bf16<<<dim3(1, MM / 128), 256, 0, stream>>>(xb, WT, f1, nullptr, MM, 128, DD);
  cast_f32_bf16<<<(MM * 128 / 4 + 255) / 256, 256, 0, stream>>>(f1, f1b, MM * 128 / 4);
  transpose_cast<<<dim3(HD / 32, 128 / 32), tb, 0, stream>>>(Wf2, WT, 128, HD);
  gemm_bf16<<<gemm_grid, 256, 0, stream>>>(f1b, WT, P, nullptr, MM, HD, 128);
  gexp_kernel<<<(MM * HD + 255) / 256, 256, 0, stream>>>(P, A_log, dt_bias, geb, MM * HD);

  // gate = x@Wg + bg
  transpose_cast<<<dim3(HD / 32, DD / 32), tb, 0, stream>>>(Wg, WT, DD, HD);
  gemm_bf16<<<gemm_grid, 256, 0, stream>>>(xb, WT, gateb, bg, MM, HD, DD);

  // chunked-pipeline delta-rule scan (16-lane cols, parity-split LDS reads)
  scan_kernel<<<BB * HH * 8, 256, 0, stream>>>(qb, kb, vb, geb, betab, ob);

  // gated RMSNorm -> bf16
  out_norm_kernel<<<MM, 256, 0, stream>>>(ob, gateb, onw, onb);

  // final projection
  transpose_cast<<<dim3(DD / 32, HD / 32), tb, 0, stream>>>(Wo, WT, HD, DD);
  gemm_bf16<<<dim3(DD / 128, MM / 128), 256, 0, stream>>>(onb, WT, out, nullptr, MM, DD, HD);
}

// Round 5
// 1184.500 us; speedup vs baseline: 1.1022x; 1.0195x over previous
//
#include <hip/hip_runtime.h>
#include <stdint.h>

// Problem constants
#define BB 2
#define TT 2048
#define DD 2048
#define HH 16
#define HD 2048     // H*Dk = H*Dv
#define MM 4096     // B*T
#define SCH 16      // scan chunk steps

typedef float f32x4 __attribute__((ext_vector_type(4)));
typedef __bf16 bf16x8 __attribute__((ext_vector_type(8)));
typedef unsigned short u16x4 __attribute__((ext_vector_type(4)));

__device__ __forceinline__ unsigned short f2b(float f) {
  unsigned int u = __float_as_uint(f);
  u += 0x7FFFu + ((u >> 16) & 1u);   // RNE
  return (unsigned short)(u >> 16);
}

__device__ __forceinline__ void async_ld16(const void* g, void* l) {
  typedef __attribute__((address_space(3))) void as3_t;
  typedef const __attribute__((address_space(1))) void as1_t;
  // NOTE: LDS arg must be WAVE-UNIFORM base; HW adds lane*16 itself.
  __builtin_amdgcn_global_load_lds((as1_t*)(uintptr_t)g,
                                   (as3_t*)(unsigned int)(uintptr_t)l, 16, 0, 0);
}

// ---- DPP 16-lane all-reduce (VALU-pipe; avoids ds_swizzle ~120cyc latency) ----
template <int CTRL>
__device__ __forceinline__ float dpp_add(float x) {
  int y = __builtin_amdgcn_update_dpp(0, __float_as_int(x), CTRL, 0xF, 0xF, false);
  return x + __int_as_float(y);
}
__device__ __forceinline__ float reduce16(float x) {
  x = dpp_add<0xB1>(x);    // quad_perm [1,0,3,2]  (xor 1)
  x = dpp_add<0x4E>(x);    // quad_perm [2,3,0,1]  (xor 2)
  x = dpp_add<0x124>(x);   // row_ror:4
  x = dpp_add<0x128>(x);   // row_ror:8
  return x;                // all 16 lanes hold the row sum
}

// ---------------- cast f32 -> bf16 (vectorized x4) ----------------
__global__ __launch_bounds__(256) void cast_f32_bf16(const float* __restrict__ in,
                                                     unsigned short* __restrict__ out,
                                                     int n4) {
  int i = blockIdx.x * 256 + threadIdx.x;
  if (i >= n4) return;
  f32x4 v = *(const f32x4*)(in + (size_t)i * 4);
  u16x4 r;
  #pragma unroll
  for (int j = 0; j < 4; j++) r[j] = f2b(v[j]);
  *(u16x4*)(out + (size_t)i * 4) = r;
}

// ---------------- transpose + cast: in f32 [R,C] -> out bf16 [C,R] ----------------
__global__ __launch_bounds__(256) void transpose_cast(const float* __restrict__ in,
                                                      unsigned short* __restrict__ out,
                                                      int R, int C) {
  __shared__ float tile[32][33];
  int bx = blockIdx.x * 32, by = blockIdx.y * 32;
  int tx = threadIdx.x, ty = threadIdx.y;
  #pragma unroll
  for (int i = 0; i < 32; i += 8)
    tile[ty + i][tx] = in[(size_t)(by + ty + i) * C + bx + tx];
  __syncthreads();
  #pragma unroll
  for (int i = 0; i < 32; i += 8)
    out[(size_t)(bx + ty + i) * R + by + tx] = f2b(tile[tx][ty + i]);
}

// ---------------- bf16 GEMM: C[M,N] f32 = A[M,K] @ Bt[N,K]^T (+bias) ----------------
// Tile remap: XCD c (dispatch id%8) gets a CONTIGUOUS range of tile ids, so the
// 16 N-tiles sharing one A row-panel land on the SAME XCD's L2 (T1). Bijective
// when grid total % 8 == 0 (all our grids: 512/128/32).
__global__ __launch_bounds__(256) void gemm_bf16(const unsigned short* __restrict__ A,
                                                 const unsigned short* __restrict__ Bt,
                                                 float* __restrict__ C,
                                                 const float* __restrict__ bias,
                                                 int M, int N, int K) {
  __shared__ __align__(16) unsigned short As[128 * 32];
  __shared__ __align__(16) unsigned short Bs[128 * 32];
  int tid = threadIdx.x;
  int l = tid & 63, w = tid >> 6;

  int nbx = gridDim.x;
  int tot = nbx * gridDim.y;
  int id = blockIdx.y * nbx + blockIdx.x;
  int nid = id;
  if ((tot & 7) == 0) {
    int per = tot >> 3;
    nid = (id & 7) * per + (id >> 3);
  }
  int row0 = (nid / nbx) * 128, col0 = (nid % nbx) * 128;

  int wm = (w >> 1) * 64, wn = (w & 1) * 64;
  const f32x4 fz = {0.f, 0.f, 0.f, 0.f};
  f32x4 acc[4][4];
  #pragma unroll
  for (int i = 0; i < 4; i++)
    #pragma unroll
    for (int j = 0; j < 4; j++) acc[i][j] = fz;

  int srow = l >> 2, skoff = (l & 3) * 8;
  int quad = l >> 4, mrow = l & 15;

  for (int kt = 0; kt < K; kt += 32) {
    #pragma unroll
    for (int i = 0; i < 2; i++) {
      int c = w * 2 + i;
      const unsigned short* gA = A + (size_t)(row0 + c * 16 + srow) * K + kt + skoff;
      const unsigned short* gB = Bt + (size_t)(col0 + c * 16 + srow) * K + kt + skoff;
      async_ld16(gA, As + c * 512);
      async_ld16(gB, Bs + c * 512);
    }
    __syncthreads();
    bf16x8 af[4], bfr[4];
    #pragma unroll
    for (int i = 0; i < 4; i++)
      af[i] = *(const bf16x8*)(As + (wm + i * 16 + mrow) * 32 + quad * 8);
    #pragma unroll
    for (int j = 0; j < 4; j++)
      bfr[j] = *(const bf16x8*)(Bs + (wn + j * 16 + mrow) * 32 + quad * 8);
    #pragma unroll
    for (int i = 0; i < 4; i++)
      #pragma unroll
      for (int j = 0; j < 4; j++)
        acc[i][j] = __builtin_amdgcn_mfma_f32_16x16x32_bf16(af[i], bfr[j], acc[i][j], 0, 0, 0);
    __syncthreads();
  }
  #pragma unroll
  for (int i = 0; i < 4; i++) {
    #pragma unroll
    for (int j = 0; j < 4; j++) {
      #pragma unroll
      for (int r = 0; r < 4; r++) {
        int rr = row0 + wm + i * 16 + quad * 4 + r;
        int cc = col0 + wn + j * 16 + mrow;
        float v = acc[i][j][r];
        if (bias) v += bias[cc];
        C[(size_t)rr * N + cc] = v;
      }
    }
  }
}

// ---------------- causal depthwise conv(K=4) + SiLU (+ per-head l2norm) ----------------
// Writes [B,H,T,128] layout for the scan. post_mul folds the scan's q-scale
// into the l2norm multiplier (free: one extra mul on rs, not per element).
__global__ __launch_bounds__(256) void conv_silu_kernel(const float* __restrict__ Pre,
                                                        const float* __restrict__ cw,
                                                        float* __restrict__ outp,
                                                        int do_norm, float post_mul) {
  int bt = blockIdx.x;
  int b = bt >> 11, t = bt & (TT - 1);
  int tid = threadIdx.x;
  int ch0 = tid * 8;
  f32x4 wv[8];
  #pragma unroll
  for (int j = 0; j < 8; j++) wv[j] = *(const f32x4*)(cw + (size_t)(ch0 + j) * 4);
  float acc[8] = {0, 0, 0, 0, 0, 0, 0, 0};
  #pragma unroll
  for (int i = 0; i < 4; i++) {
    int tt = t - 3 + i;
    if (tt < 0) continue;
    const float* r = Pre + ((size_t)(b * TT + tt)) * HD + ch0;
    f32x4 a0 = *(const f32x4*)r;
    f32x4 a1 = *(const f32x4*)(r + 4);
    #pragma unroll
    for (int j = 0; j < 4; j++) {
      acc[j]     += a0[j] * wv[j][i];
      acc[4 + j] += a1[j] * wv[4 + j][i];
    }
  }
  float val[8];
  #pragma unroll
  for (int j = 0; j < 8; j++) val[j] = acc[j] / (1.f + expf(-acc[j]));   // SiLU
  if (do_norm) {
    float ss = 0.f;
    #pragma unroll
    for (int j = 0; j < 8; j++) ss += val[j] * val[j];
    ss = reduce16(ss);
    float rs = rsqrtf(ss + 1e-6f) * post_mul;
    #pragma unroll
    for (int j = 0; j < 8; j++) val[j] *= rs;
  }
  int h = tid >> 4, cc = (tid & 15) * 8;
  float* op = outp + (((size_t)(b * HH + h)) * TT + t) * 128 + cc;
  f32x4 o0, o1;
  #pragma unroll
  for (int j = 0; j < 4; j++) { o0[j] = val[j]; o1[j] = val[4 + j]; }
  *(f32x4*)op = o0;
  *(f32x4*)(op + 4) = o1;
}

// ---------------- beta = sigmoid(x @ Wb) -> [B,H,T] layout ----------------
__global__ __launch_bounds__(256) void beta_kernel(const float* __restrict__ x,
                                                   const float* __restrict__ Wb,
                                                   float* __restrict__ beta) {
  __shared__ float xs[2048];
  int bt = blockIdx.x, tid = threadIdx.x;
  int b = bt >> 11, t = bt & (TT - 1);
  const float* row = x + (size_t)bt * DD;
  #pragma unroll
  for (int i = 0; i < 2; i++)
    *(f32x4*)(xs + tid * 8 + i * 4) = *(const f32x4*)(row + tid * 8 + i * 4);
  __syncthreads();
  int h = tid >> 4, seg = tid & 15;
  float p = 0.f;
  for (int j = 0; j < 128; j++) {
    int d = seg * 128 + ((j + seg * 9) & 127);
    p += xs[d] * Wb[(size_t)d * HH + h];
  }
  p = reduce16(p);
  if (seg == 0) beta[((size_t)(b * HH + h)) * TT + t] = 1.f / (1.f + expf(-p));
}

// ---------------- gexp -> [B,H,T,128] layout ----------------
__global__ __launch_bounds__(256) void gexp_kernel(const float* __restrict__ g,
                                                   const float* __restrict__ A_log,
                                                   const float* __restrict__ dt_bias,
                                                   float* __restrict__ ge, int n) {
  int i = blockIdx.x * 256 + threadIdx.x;
  if (i >= n) return;
  int bt = i >> 11, ch = i & (HD - 1);
  int b = bt >> 11, t = bt & (TT - 1);
  int h = ch >> 7, c = ch & 127;
  float gv = g[i] + dt_bias[ch];
  float sp = (gv > 20.f) ? gv : log1pf(expf(gv));
  ge[(((size_t)(b * HH + h)) * TT + t) * 128 + c] = expf(-expf(A_log[h]) * sp);
}

// ---------------- KDA delta-rule scan: 16-lane cols, 2-deep prefetch pipeline ----------------
// r4 post-mortem: conflicts=0 but step ~400cyc vs issue 132 + chain ~100 ->
// ~170cyc exposed LDS latency / scheduling slack at 88 VGPR (compiler kept a
// minimal window). Fixes:
//  * __launch_bounds__(256,1): lift VGPR cap (we need only 1 wave/SIMD anyway)
//  * explicit 2-step-deep register pipeline: step s issues step s+2's 6
//    ds_read_b128 BEFORE the chain; consumption is 2 steps (~500cyc) later,
//    so LDS latency is structurally hidden; po-reduce of step s fills step
//    s+1's chain stalls.
// Parity-split reads (r4, conflict-free); per-chunk v*beta/beta reg preload;
// cndmask-keep store; q pre-scaled; kg=k*g off the recurrence path.
// blk mapping: bh = blk&31 puts all 8 col-blocks of one (b,h) on the same XCD.
// v and o alias: block only touches its own 16 columns; writes strictly behind reads.
__global__ __launch_bounds__(256, 1) void scan_kernel(const float* __restrict__ q,
                                                      const float* __restrict__ k,
                                                      const float* v,
                                                      const float* __restrict__ ge,
                                                      const float* __restrict__ beta,
                                                      float* o) {
  __shared__ __align__(16) float kbuf[2][SCH * 128];
  __shared__ __align__(16) float gbuf[2][SCH * 128];
  __shared__ __align__(16) float qbuf[2][SCH * 128];
  __shared__ __align__(16) float vbuf[2][SCH * 16];
  __shared__ __align__(16) float bbuf[TT];

  int blk = blockIdx.x;
  int bh = blk & 31;                        // same-bh blocks share an XCD
  int colblk = blk >> 5;                    // 0..7
  int tid = threadIdx.x;
  int w = tid >> 6, l = tid & 63;
  int grp = l >> 4, i = l & 15;
  int lcol = w * 4 + grp;                   // 0..15: column within block
  int col = colblk * 16 + lcol;             // 0..127: column within head

  // Parity-split 16B-unit offsets: groups 0,2 -> (even,odd); 1,3 -> (odd,even).
  // Wave-wide: each read presents 32 DISTINCT units at 2-fold multiplicity.
  int par = grp & 1;
  int of0 = (2 * i + par) * 4;              // float offset of lane's first 16B
  int of1 = (2 * i + (1 - par)) * 4;        // float offset of lane's second 16B

  const float* kbh = k    + (size_t)bh * TT * 128;
  const float* gbh = ge   + (size_t)bh * TT * 128;
  const float* qbh = q    + (size_t)bh * TT * 128;
  const float* vbh = v    + (size_t)bh * TT * 128;
  const float* bbh = beta + (size_t)bh * TT;
  float* obh = o + (size_t)bh * TT * 128;

  // stage whole beta sequence (8 KB) once
  #pragma unroll
  for (int j = 0; j < 2; j++) {
    int jj = w * 2 + j;
    async_ld16(bbh + jj * 256 + l * 4, (float*)bbuf + jj * 256);
  }
  // cooperative staging (wave role), contiguous source + linear LDS
  auto stage = [&](int cidx, int nb) {
    size_t t0 = (size_t)cidx * SCH;
    if (w == 0) {
      #pragma unroll
      for (int j = 0; j < 8; j++)
        async_ld16(kbh + t0 * 128 + j * 256 + l * 4, (float*)kbuf[nb] + j * 256);
    } else if (w == 1) {
      #pragma unroll
      for (int j = 0; j < 8; j++)
        async_ld16(gbh + t0 * 128 + j * 256 + l * 4, (float*)gbuf[nb] + j * 256);
    } else if (w == 2) {
      #pragma unroll
      for (int j = 0; j < 8; j++)
        async_ld16(qbh + t0 * 128 + j * 256 + l * 4, (float*)qbuf[nb] + j * 256);
    } else {
      async_ld16(vbh + (t0 + (size_t)(l >> 2)) * 128 + colblk * 16 + (l & 3) * 4,
                 (float*)vbuf[nb]);
    }
  };
  stage(0, 0);
  __syncthreads();

  f32x4 s0 = {0.f, 0.f, 0.f, 0.f}, s1 = {0.f, 0.f, 0.f, 0.f};
  float okeep = 0.f;

  for (int c = 0; c < TT / SCH; c++) {
    int cb = c & 1, nb = cb ^ 1;
    // async-stage next chunk; latency hidden behind 16 compute steps
    if (c + 1 < TT / SCH) stage(c + 1, nb);

    const float* kc = (const float*)kbuf[cb];
    const float* gc = (const float*)gbuf[cb];
    const float* qc = (const float*)qbuf[cb];
    // per-chunk preload: v*beta and beta into registers (waits off step loop)
    float vbt[SCH], btp[SCH];
    #pragma unroll
    for (int s = 0; s < SCH; s++) {
      float vv = ((const float*)vbuf[cb])[s * 16 + lcol];  // 16-lane broadcast
      float bb = bbuf[c * SCH + s];                        // uniform
      btp[s] = bb;
      vbt[s] = vv * bb;
    }
    // 2-deep pipeline prologue: steps 0 and 1 into registers
    f32x4 ka0 = *(const f32x4*)(kc + of0), ka1 = *(const f32x4*)(kc + of1);
    f32x4 ga0 = *(const f32x4*)(gc + of0), ga1 = *(const f32x4*)(gc + of1);
    f32x4 qa0 = *(const f32x4*)(qc + of0), qa1 = *(const f32x4*)(qc + of1);
    f32x4 kb0 = *(const f32x4*)(kc + 128 + of0), kb1 = *(const f32x4*)(kc + 128 + of1);
    f32x4 gb0 = *(const f32x4*)(gc + 128 + of0), gb1 = *(const f32x4*)(gc + 128 + of1);
    f32x4 qb0 = *(const f32x4*)(qc + 128 + of0), qb1 = *(const f32x4*)(qc + 128 + of1);
    #pragma unroll
    for (int s = 0; s < SCH; s++) {
      // issue step s+2's loads FIRST: consumed 2 steps later -> latency hidden
      f32x4 kf0, kf1, gf0, gf1, qf0, qf1;
      if (s + 2 < SCH) {
        const float* kp = kc + (s + 2) * 128;
        const float* gp = gc + (s + 2) * 128;
        const float* qp = qc + (s + 2) * 128;
        kf0 = *(const f32x4*)(kp + of0); kf1 = *(const f32x4*)(kp + of1);
        gf0 = *(const f32x4*)(gp + of0); gf1 = *(const f32x4*)(gp + of1);
        qf0 = *(const f32x4*)(qp + of0); qf1 = *(const f32x4*)(qp + of1);
      }
      // p = k . (S*g) = (k*g) . S_old  -- decay off the critical path
      f32x4 kg0 = ka0 * ga0, kg1 = ka1 * ga1;
      f32x4 pp = kg0 * s0 + kg1 * s1;
      float p = (pp[0] + pp[1]) + (pp[2] + pp[3]);
      p = reduce16(p);                       // DPP butterfly on the path
      s0 *= ga0; s1 *= ga1;                  // decay (overlaps the reduce)
      float u = fmaf(-btp[s], p, vbt[s]);    // u = (v - p)*beta, one FMA on path
      s0 += ka0 * u; s1 += ka1 * u;
      f32x4 oo = qa0 * s0 + qa1 * s1;        // q pre-scaled by 128^-0.5
      float po = (oo[0] + oo[1]) + (oo[2] + oo[3]);
      po = reduce16(po);                     // off the recurrence path
      okeep = (i == s) ? po : okeep;         // cndmask, no divergence
      // rotate the 2-deep pipeline
      if (s + 1 < SCH) {
        ka0 = kb0; ka1 = kb1; ga0 = gb0; ga1 = gb1; qa0 = qb0; qa1 = qb1;
        if (s + 2 < SCH) {
          kb0 = kf0; kb1 = kf1; gb0 = gf0; gb1 = gf1; qb0 = qf0; qb1 = qf1;
        }
      }
    }
    // one store per chunk: lane i holds step i's output for its column
    obh[((size_t)c * SCH + i) * 128 + col] = okeep;
    __syncthreads();
  }
}

// ---------------- gated RMSNorm -> bf16 (o in [B,H,T,128]) ----------------
__global__ __launch_bounds__(256) void out_norm_kernel(const float* o,
                                                       const float* __restrict__ gate,
                                                       const float* __restrict__ w,
                                                       unsigned short* __restrict__ onb) {
  int bt = blockIdx.x, tid = threadIdx.x;
  int b = bt >> 11, t = bt & (TT - 1);
  int h = tid >> 4, seg = tid & 15;
  size_t obase = (((size_t)(b * HH + h)) * TT + t) * 128 + seg * 8;
  size_t gbase = (size_t)bt * HD + (size_t)h * 128 + seg * 8;
  f32x4 o0 = *(const f32x4*)(o + obase);
  f32x4 o1 = *(const f32x4*)(o + obase + 4);
  float ss = 0.f;
  #pragma unroll
  for (int j = 0; j < 4; j++) ss += o0[j] * o0[j] + o1[j] * o1[j];
  ss = reduce16(ss);
  float rs = rsqrtf(ss * (1.f / 128.f) + 1e-5f);
  u16x4 r0, r1;
  #pragma unroll
  for (int j = 0; j < 4; j++) {
    float gv0 = gate[gbase + j];
    float gv1 = gate[gbase + 4 + j];
    float a0 = o0[j] * rs * w[seg * 8 + j] * (gv0 / (1.f + expf(-gv0)));
    float a1 = o1[j] * rs * w[seg * 8 + 4 + j] * (gv1 / (1.f + expf(-gv1)));
    r0[j] = f2b(a0);
    r1[j] = f2b(a1);
  }
  *(u16x4*)(onb + gbase) = r0;
  *(u16x4*)(onb + gbase + 4) = r1;
}

// ---------------- driver ----------------
extern "C" void kernel_launch(void* const* d_in, const int* in_sizes, int n_in,
                              void* d_out, int out_size, void* d_ws, size_t ws_size,
                              hipStream_t stream) {
  const float* x       = (const float*)d_in[0];
  const float* Wq      = (const float*)d_in[1];
  const float* Wk      = (const float*)d_in[2];
  const float* Wv      = (const float*)d_in[3];
  const float* cq      = (const float*)d_in[4];
  const float* ck      = (const float*)d_in[5];
  const float* cv      = (const float*)d_in[6];
  const float* Wf1     = (const float*)d_in[7];
  const float* Wf2     = (const float*)d_in[8];
  const float* Wb      = (const float*)d_in[9];
  const float* A_log   = (const float*)d_in[10];
  const float* dt_bias = (const float*)d_in[11];
  const float* Wg      = (const float*)d_in[12];
  const float* bg      = (const float*)d_in[13];
  const float* onw     = (const float*)d_in[14];
  const float* Wo      = (const float*)d_in[15];
  float* out = (float*)d_out;

  char* ws = (char*)d_ws;
  unsigned short* WT  = (unsigned short*)(ws);                       //  8 MB rotating W^T
  unsigned short* xb  = (unsigned short*)(ws + ((size_t)8  << 20));  // 16 MB bf16 x
  float* P    = (float*)(ws + ((size_t)24  << 20));                  // 32 MB rotating pre/gate
  float* qb   = (float*)(ws + ((size_t)56  << 20));                  // 32 MB [B,H,T,128]
  float* kb   = (float*)(ws + ((size_t)88  << 20));                  // 32 MB [B,H,T,128]
  float* vb   = (float*)(ws + ((size_t)120 << 20));                  // 32 MB (aliased by o)
  float* geb  = (float*)(ws + ((size_t)152 << 20));                  // 32 MB [B,H,T,128]
  float* betab= (float*)(ws + ((size_t)184 << 20));                  // 256 KB [B,H,T]
  float* f1   = (float*)(ws + ((size_t)185 << 20));                  //   2 MB
  unsigned short* f1b = (unsigned short*)(ws + ((size_t)187 << 20)); //   1 MB
  unsigned short* onb = xb;   // xb dead after gate GEMM
  float* gateb = P;           // P reused as gate buffer
  float* ob    = vb;          // scan output aliases v

  dim3 tb(32, 8);
  dim3 gemm_grid(HD / 128, MM / 128);

  cast_f32_bf16<<<(MM * DD / 4 + 255) / 256, 256, 0, stream>>>(x, xb, MM * DD / 4);

  // q path (scan scale 128^-0.5 folded into l2norm)
  transpose_cast<<<dim3(HD / 32, DD / 32), tb, 0, stream>>>(Wq, WT, DD, HD);
  gemm_bf16<<<gemm_grid, 256, 0, stream>>>(xb, WT, P, nullptr, MM, HD, DD);
  conv_silu_kernel<<<MM, 256, 0, stream>>>(P, cq, qb, 1, 0.08838834764831845f);
  // k path
  transpose_cast<<<dim3(HD / 32, DD / 32), tb, 0, stream>>>(Wk, WT, DD, HD);
  gemm_bf16<<<gemm_grid, 256, 0, stream>>>(xb, WT, P, nullptr, MM, HD, DD);
  conv_silu_kernel<<<MM, 256, 0, stream>>>(P, ck, kb, 1, 1.0f);
  // v path
  transpose_cast<<<dim3(HD / 32, DD / 32), tb, 0, stream>>>(Wv, WT, DD, HD);
  gemm_bf16<<<gemm_grid, 256, 0, stream>>>(xb, WT, P, nullptr, MM, HD, DD);
  conv_silu_kernel<<<MM, 256, 0, stream>>>(P, cv, vb, 0, 1.0f);

  // beta
  beta_kernel<<<MM, 256, 0, stream>>>(x, Wb, betab);

  // g chain
  transpose_cast<<<dim3(128 / 32, DD / 32), tb, 0, stream>>>(Wf1, WT, DD, 128);
  gemm_bf16<<<dim3(1, MM / 128), 256, 0, stream>>>(xb, WT, f1, nullptr, MM, 128, DD);
  cast_f32_bf16<<<(MM * 128 / 4 + 255) / 256, 256, 0, stream>>>(f1, f1b, MM * 128 / 4);
  transpose_cast<<<dim3(HD / 32, 128 / 32), tb, 0, stream>>>(Wf2, WT, 128, HD);
  gemm_bf16<<<gemm_grid, 256, 0, stream>>>(f1b, WT, P, nullptr, MM, HD, 128);
  gexp_kernel<<<(MM * HD + 255) / 256, 256, 0, stream>>>(P, A_log, dt_bias, geb, MM * HD);

  // gate = x@Wg + bg
  transpose_cast<<<dim3(HD / 32, DD / 32), tb, 0, stream>>>(Wg, WT, DD, HD);
  gemm_bf16<<<gemm_grid, 256, 0, stream>>>(xb, WT, gateb, bg, MM, HD, DD);

  // chunked-pipeline delta-rule scan (2-deep register pipeline)
  scan_kernel<<<BB * HH * 8, 256, 0, stream>>>(qb, kb, vb, geb, betab, ob);

  // gated RMSNorm -> bf16
  out_norm_kernel<<<MM, 256, 0, stream>>>(ob, gateb, onw, onb);

  // final projection
  transpose_cast<<<dim3(DD / 32, HD / 32), tb, 0, stream>>>(Wo, WT, HD, DD);
  gemm_bf16<<<dim3(DD / 128, MM / 128), 256, 0, stream>>>(onb, WT, out, nullptr, MM, DD, HD);
}

// Round 7
// 1184.118 us; speedup vs baseline: 1.1026x; 1.0003x over previous
//
#include <hip/hip_runtime.h>
#include <stdint.h>

// Problem constants
#define BB 2
#define TT 2048
#define DD 2048
#define HH 16
#define HD 2048     // H*Dk = H*Dv
#define MM 4096     // B*T
#define SCH 16      // scan chunk steps

typedef float f32x4 __attribute__((ext_vector_type(4)));
typedef __bf16 bf16x8 __attribute__((ext_vector_type(8)));
typedef unsigned short u16x4 __attribute__((ext_vector_type(4)));

__device__ __forceinline__ unsigned short f2b(float f) {
  unsigned int u = __float_as_uint(f);
  u += 0x7FFFu + ((u >> 16) & 1u);   // RNE
  return (unsigned short)(u >> 16);
}

__device__ __forceinline__ void async_ld16(const void* g, void* l) {
  typedef __attribute__((address_space(3))) void as3_t;
  typedef const __attribute__((address_space(1))) void as1_t;
  // NOTE: LDS arg must be WAVE-UNIFORM base; HW adds lane*16 itself.
  __builtin_amdgcn_global_load_lds((as1_t*)(uintptr_t)g,
                                   (as3_t*)(unsigned int)(uintptr_t)l, 16, 0, 0);
}

// ---- DPP 16-lane all-reduce (VALU-pipe; avoids ds_swizzle ~120cyc latency) ----
// NOTE (r6 lesson): keep this as the BUILTIN form. A raw-asm fused
// v_add_f32_dpp chain violates the "VALU write -> DPP read needs 2 wait
// states" hazard (compiler inserts the nops only for builtin-generated DPP);
// r6's asm version silently computed garbage (absmax 3.38).
template <int CTRL>
__device__ __forceinline__ float dpp_add(float x) {
  int y = __builtin_amdgcn_update_dpp(0, __float_as_int(x), CTRL, 0xF, 0xF, false);
  return x + __int_as_float(y);
}
__device__ __forceinline__ float reduce16(float x) {
  x = dpp_add<0xB1>(x);    // quad_perm [1,0,3,2]  (xor 1)
  x = dpp_add<0x4E>(x);    // quad_perm [2,3,0,1]  (xor 2)
  x = dpp_add<0x124>(x);   // row_ror:4
  x = dpp_add<0x128>(x);   // row_ror:8
  return x;                // all 16 lanes hold the row sum
}

// ---------------- cast f32 -> bf16 (vectorized x4) ----------------
__global__ __launch_bounds__(256) void cast_f32_bf16(const float* __restrict__ in,
                                                     unsigned short* __restrict__ out,
                                                     int n4) {
  int i = blockIdx.x * 256 + threadIdx.x;
  if (i >= n4) return;
  f32x4 v = *(const f32x4*)(in + (size_t)i * 4);
  u16x4 r;
  #pragma unroll
  for (int j = 0; j < 4; j++) r[j] = f2b(v[j]);
  *(u16x4*)(out + (size_t)i * 4) = r;
}

// ---------------- transpose + cast: in f32 [R,C] -> out bf16 [C,R] ----------------
__global__ __launch_bounds__(256) void transpose_cast(const float* __restrict__ in,
                                                      unsigned short* __restrict__ out,
                                                      int R, int C) {
  __shared__ float tile[32][33];
  int bx = blockIdx.x * 32, by = blockIdx.y * 32;
  int tx = threadIdx.x, ty = threadIdx.y;
  #pragma unroll
  for (int i = 0; i < 32; i += 8)
    tile[ty + i][tx] = in[(size_t)(by + ty + i) * C + bx + tx];
  __syncthreads();
  #pragma unroll
  for (int i = 0; i < 32; i += 8)
    out[(size_t)(bx + ty + i) * R + by + tx] = f2b(tile[tx][ty + i]);
}

// ---------------- bf16 GEMM: C[M,N] f32 = A[M,K] @ Bt[N,K]^T (+bias) ----------------
// Tile remap: XCD c (dispatch id%8) gets a CONTIGUOUS range of tile ids, so the
// 16 N-tiles sharing one A row-panel land on the SAME XCD's L2 (T1). Bijective
// when grid total % 8 == 0 (all our grids: 512/128/32).
__global__ __launch_bounds__(256) void gemm_bf16(const unsigned short* __restrict__ A,
                                                 const unsigned short* __restrict__ Bt,
                                                 float* __restrict__ C,
                                                 const float* __restrict__ bias,
                                                 int M, int N, int K) {
  __shared__ __align__(16) unsigned short As[128 * 32];
  __shared__ __align__(16) unsigned short Bs[128 * 32];
  int tid = threadIdx.x;
  int l = tid & 63, w = tid >> 6;

  int nbx = gridDim.x;
  int tot = nbx * gridDim.y;
  int id = blockIdx.y * nbx + blockIdx.x;
  int nid = id;
  if ((tot & 7) == 0) {
    int per = tot >> 3;
    nid = (id & 7) * per + (id >> 3);
  }
  int row0 = (nid / nbx) * 128, col0 = (nid % nbx) * 128;

  int wm = (w >> 1) * 64, wn = (w & 1) * 64;
  const f32x4 fz = {0.f, 0.f, 0.f, 0.f};
  f32x4 acc[4][4];
  #pragma unroll
  for (int i = 0; i < 4; i++)
    #pragma unroll
    for (int j = 0; j < 4; j++) acc[i][j] = fz;

  int srow = l >> 2, skoff = (l & 3) * 8;
  int quad = l >> 4, mrow = l & 15;

  for (int kt = 0; kt < K; kt += 32) {
    #pragma unroll
    for (int i = 0; i < 2; i++) {
      int c = w * 2 + i;
      const unsigned short* gA = A + (size_t)(row0 + c * 16 + srow) * K + kt + skoff;
      const unsigned short* gB = Bt + (size_t)(col0 + c * 16 + srow) * K + kt + skoff;
      async_ld16(gA, As + c * 512);
      async_ld16(gB, Bs + c * 512);
    }
    __syncthreads();
    bf16x8 af[4], bfr[4];
    #pragma unroll
    for (int i = 0; i < 4; i++)
      af[i] = *(const bf16x8*)(As + (wm + i * 16 + mrow) * 32 + quad * 8);
    #pragma unroll
    for (int j = 0; j < 4; j++)
      bfr[j] = *(const bf16x8*)(Bs + (wn + j * 16 + mrow) * 32 + quad * 8);
    #pragma unroll
    for (int i = 0; i < 4; i++)
      #pragma unroll
      for (int j = 0; j < 4; j++)
        acc[i][j] = __builtin_amdgcn_mfma_f32_16x16x32_bf16(af[i], bfr[j], acc[i][j], 0, 0, 0);
    __syncthreads();
  }
  #pragma unroll
  for (int i = 0; i < 4; i++) {
    #pragma unroll
    for (int j = 0; j < 4; j++) {
      #pragma unroll
      for (int r = 0; r < 4; r++) {
        int rr = row0 + wm + i * 16 + quad * 4 + r;
        int cc = col0 + wn + j * 16 + mrow;
        float v = acc[i][j][r];
        if (bias) v += bias[cc];
        C[(size_t)rr * N + cc] = v;
      }
    }
  }
}

// ---------------- causal depthwise conv(K=4) + SiLU (+ per-head l2norm) ----------------
// Writes [B,H,T,128] layout for the scan. post_mul folds the scan's q-scale
// into the l2norm multiplier (free: one extra mul on rs, not per element).
__global__ __launch_bounds__(256) void conv_silu_kernel(const float* __restrict__ Pre,
                                                        const float* __restrict__ cw,
                                                        float* __restrict__ outp,
                                                        int do_norm, float post_mul) {
  int bt = blockIdx.x;
  int b = bt >> 11, t = bt & (TT - 1);
  int tid = threadIdx.x;
  int ch0 = tid * 8;
  f32x4 wv[8];
  #pragma unroll
  for (int j = 0; j < 8; j++) wv[j] = *(const f32x4*)(cw + (size_t)(ch0 + j) * 4);
  float acc[8] = {0, 0, 0, 0, 0, 0, 0, 0};
  #pragma unroll
  for (int i = 0; i < 4; i++) {
    int tt = t - 3 + i;
    if (tt < 0) continue;
    const float* r = Pre + ((size_t)(b * TT + tt)) * HD + ch0;
    f32x4 a0 = *(const f32x4*)r;
    f32x4 a1 = *(const f32x4*)(r + 4);
    #pragma unroll
    for (int j = 0; j < 4; j++) {
      acc[j]     += a0[j] * wv[j][i];
      acc[4 + j] += a1[j] * wv[4 + j][i];
    }
  }
  float val[8];
  #pragma unroll
  for (int j = 0; j < 8; j++) val[j] = acc[j] / (1.f + expf(-acc[j]));   // SiLU
  if (do_norm) {
    float ss = 0.f;
    #pragma unroll
    for (int j = 0; j < 8; j++) ss += val[j] * val[j];
    ss = reduce16(ss);
    float rs = rsqrtf(ss + 1e-6f) * post_mul;
    #pragma unroll
    for (int j = 0; j < 8; j++) val[j] *= rs;
  }
  int h = tid >> 4, cc = (tid & 15) * 8;
  float* op = outp + (((size_t)(b * HH + h)) * TT + t) * 128 + cc;
  f32x4 o0, o1;
  #pragma unroll
  for (int j = 0; j < 4; j++) { o0[j] = val[j]; o1[j] = val[4 + j]; }
  *(f32x4*)op = o0;
  *(f32x4*)(op + 4) = o1;
}

// ---------------- beta = sigmoid(x @ Wb) -> [B,H,T] layout ----------------
__global__ __launch_bounds__(256) void beta_kernel(const float* __restrict__ x,
                                                   const float* __restrict__ Wb,
                                                   float* __restrict__ beta) {
  __shared__ float xs[2048];
  int bt = blockIdx.x, tid = threadIdx.x;
  int b = bt >> 11, t = bt & (TT - 1);
  const float* row = x + (size_t)bt * DD;
  #pragma unroll
  for (int i = 0; i < 2; i++)
    *(f32x4*)(xs + tid * 8 + i * 4) = *(const f32x4*)(row + tid * 8 + i * 4);
  __syncthreads();
  int h = tid >> 4, seg = tid & 15;
  float p = 0.f;
  for (int j = 0; j < 128; j++) {
    int d = seg * 128 + ((j + seg * 9) & 127);
    p += xs[d] * Wb[(size_t)d * HH + h];
  }
  p = reduce16(p);
  if (seg == 0) beta[((size_t)(b * HH + h)) * TT + t] = 1.f / (1.f + expf(-p));
}

// ---------------- gexp -> [B,H,T,128] layout ----------------
__global__ __launch_bounds__(256) void gexp_kernel(const float* __restrict__ g,
                                                   const float* __restrict__ A_log,
                                                   const float* __restrict__ dt_bias,
                                                   float* __restrict__ ge, int n) {
  int i = blockIdx.x * 256 + threadIdx.x;
  if (i >= n) return;
  int bt = i >> 11, ch = i & (HD - 1);
  int b = bt >> 11, t = bt & (TT - 1);
  int h = ch >> 7, c = ch & 127;
  float gv = g[i] + dt_bias[ch];
  float sp = (gv > 20.f) ? gv : log1pf(expf(gv));
  ge[(((size_t)(b * HH + h)) * TT + t) * 128 + c] = expf(-expf(A_log[h]) * sp);
}

// ---------------- KDA delta-rule scan ----------------
// r6 post-mortem: the fused-asm DPP reduce violated the VALU-write->DPP-read
// hazard (no compiler nops inside asm) -> wrong results. Reverted to builtin
// reduce16. This round isolates the OTHER r6 change, which is semantics-free:
//  * 1-deep prefetch PINNED with sched_barrier(0): the 6 ds_read_b128 for
//    step s+1 cannot sink into the chain -> issued a full chain (~250cyc)
//    before their lgkmcnt wait.
// Parity-split reads (r4, conflict-free: 32 distinct 16B units @ 2-fold
// multiplicity); per-chunk v*beta/beta reg preload; cndmask-keep store; q
// pre-scaled; kg=k*g off the recurrence path. bh=blk&31 XCD mapping (L2 dedup).
// v and o alias: block only touches its own 16 columns; writes strictly behind reads.
__global__ __launch_bounds__(256, 1) void scan_kernel(const float* __restrict__ q,
                                                      const float* __restrict__ k,
                                                      const float* v,
                                                      const float* __restrict__ ge,
                                                      const float* __restrict__ beta,
                                                      float* o) {
  __shared__ __align__(16) float kbuf[2][SCH * 128];
  __shared__ __align__(16) float gbuf[2][SCH * 128];
  __shared__ __align__(16) float qbuf[2][SCH * 128];
  __shared__ __align__(16) float vbuf[2][SCH * 16];
  __shared__ __align__(16) float bbuf[TT];

  int blk = blockIdx.x;
  int bh = blk & 31;                        // same-bh blocks share an XCD
  int colblk = blk >> 5;                    // 0..7
  int tid = threadIdx.x;
  int w = tid >> 6, l = tid & 63;
  int grp = l >> 4, i = l & 15;
  int lcol = w * 4 + grp;                   // 0..15: column within block
  int col = colblk * 16 + lcol;             // 0..127: column within head

  // Parity-split 16B-unit offsets: groups 0,2 -> (even,odd); 1,3 -> (odd,even).
  int par = grp & 1;
  int of0 = (2 * i + par) * 4;              // float offset of lane's first 16B
  int of1 = (2 * i + (1 - par)) * 4;        // float offset of lane's second 16B

  const float* kbh = k    + (size_t)bh * TT * 128;
  const float* gbh = ge   + (size_t)bh * TT * 128;
  const float* qbh = q    + (size_t)bh * TT * 128;
  const float* vbh = v    + (size_t)bh * TT * 128;
  const float* bbh = beta + (size_t)bh * TT;
  float* obh = o + (size_t)bh * TT * 128;

  // stage whole beta sequence (8 KB) once
  #pragma unroll
  for (int j = 0; j < 2; j++) {
    int jj = w * 2 + j;
    async_ld16(bbh + jj * 256 + l * 4, (float*)bbuf + jj * 256);
  }
  // cooperative staging (wave role), contiguous source + linear LDS
  auto stage = [&](int cidx, int nb) {
    size_t t0 = (size_t)cidx * SCH;
    if (w == 0) {
      #pragma unroll
      for (int j = 0; j < 8; j++)
        async_ld16(kbh + t0 * 128 + j * 256 + l * 4, (float*)kbuf[nb] + j * 256);
    } else if (w == 1) {
      #pragma unroll
      for (int j = 0; j < 8; j++)
        async_ld16(gbh + t0 * 128 + j * 256 + l * 4, (float*)gbuf[nb] + j * 256);
    } else if (w == 2) {
      #pragma unroll
      for (int j = 0; j < 8; j++)
        async_ld16(qbh + t0 * 128 + j * 256 + l * 4, (float*)qbuf[nb] + j * 256);
    } else {
      async_ld16(vbh + (t0 + (size_t)(l >> 2)) * 128 + colblk * 16 + (l & 3) * 4,
                 (float*)vbuf[nb]);
    }
  };
  stage(0, 0);
  __syncthreads();

  f32x4 s0 = {0.f, 0.f, 0.f, 0.f}, s1 = {0.f, 0.f, 0.f, 0.f};
  float okeep = 0.f;

  for (int c = 0; c < TT / SCH; c++) {
    int cb = c & 1, nb = cb ^ 1;
    // async-stage next chunk; latency hidden behind 16 compute steps
    if (c + 1 < TT / SCH) stage(c + 1, nb);

    const float* kc = (const float*)kbuf[cb];
    const float* gc = (const float*)gbuf[cb];
    const float* qc = (const float*)qbuf[cb];
    // per-chunk preload: v*beta and beta into registers (waits off step loop)
    float vbt[SCH], btp[SCH];
    #pragma unroll
    for (int s = 0; s < SCH; s++) {
      float vv = ((const float*)vbuf[cb])[s * 16 + lcol];  // 16-lane broadcast
      float bb = bbuf[c * SCH + s];                        // uniform
      btp[s] = bb;
      vbt[s] = vv * bb;
    }
    // register-rotate: step s+1 loads issued at step-top, pinned by
    // sched_barrier so they cannot sink into the chain.
    f32x4 k0 = *(const f32x4*)(kc + of0), k1 = *(const f32x4*)(kc + of1);
    f32x4 g0 = *(const f32x4*)(gc + of0), g1 = *(const f32x4*)(gc + of1);
    f32x4 q0 = *(const f32x4*)(qc + of0), q1 = *(const f32x4*)(qc + of1);
    #pragma unroll
    for (int s = 0; s < SCH; s++) {
      f32x4 k0n, k1n, g0n, g1n, q0n, q1n;
      if (s + 1 < SCH) {
        const float* kp = kc + (s + 1) * 128;
        const float* gp = gc + (s + 1) * 128;
        const float* qp = qc + (s + 1) * 128;
        k0n = *(const f32x4*)(kp + of0); k1n = *(const f32x4*)(kp + of1);
        g0n = *(const f32x4*)(gp + of0); g1n = *(const f32x4*)(gp + of1);
        q0n = *(const f32x4*)(qp + of0); q1n = *(const f32x4*)(qp + of1);
        __builtin_amdgcn_sched_barrier(0);   // pin ds_reads above the chain
      }
      // p = k . (S*g) = (k*g) . S_old  -- decay off the critical path
      f32x4 kg0 = k0 * g0, kg1 = k1 * g1;
      f32x4 pp = kg0 * s0 + kg1 * s1;
      float p = (pp[0] + pp[1]) + (pp[2] + pp[3]);
      p = reduce16(p);                       // DPP butterfly on the path
      s0 *= g0; s1 *= g1;                    // decay (overlaps the reduce)
      float u = fmaf(-btp[s], p, vbt[s]);    // u = (v - p)*beta, one FMA on path
      s0 += k0 * u; s1 += k1 * u;
      f32x4 oo = q0 * s0 + q1 * s1;          // q pre-scaled by 128^-0.5
      float po = (oo[0] + oo[1]) + (oo[2] + oo[3]);
      po = reduce16(po);                     // off the recurrence path
      okeep = (i == s) ? po : okeep;         // cndmask, no divergence
      if (s + 1 < SCH) {
        k0 = k0n; k1 = k1n; g0 = g0n; g1 = g1n; q0 = q0n; q1 = q1n;
      }
    }
    // one store per chunk: lane i holds step i's output for its column
    obh[((size_t)c * SCH + i) * 128 + col] = okeep;
    __syncthreads();
  }
}

// ---------------- gated RMSNorm -> bf16 (o in [B,H,T,128]) ----------------
__global__ __launch_bounds__(256) void out_norm_kernel(const float* o,
                                                       const float* __restrict__ gate,
                                                       const float* __restrict__ w,
                                                       unsigned short* __restrict__ onb) {
  int bt = blockIdx.x, tid = threadIdx.x;
  int b = bt >> 11, t = bt & (TT - 1);
  int h = tid >> 4, seg = tid & 15;
  size_t obase = (((size_t)(b * HH + h)) * TT + t) * 128 + seg * 8;
  size_t gbase = (size_t)bt * HD + (size_t)h * 128 + seg * 8;
  f32x4 o0 = *(const f32x4*)(o + obase);
  f32x4 o1 = *(const f32x4*)(o + obase + 4);
  float ss = 0.f;
  #pragma unroll
  for (int j = 0; j < 4; j++) ss += o0[j] * o0[j] + o1[j] * o1[j];
  ss = reduce16(ss);
  float rs = rsqrtf(ss * (1.f / 128.f) + 1e-5f);
  u16x4 r0, r1;
  #pragma unroll
  for (int j = 0; j < 4; j++) {
    float gv0 = gate[gbase + j];
    float gv1 = gate[gbase + 4 + j];
    float a0 = o0[j] * rs * w[seg * 8 + j] * (gv0 / (1.f + expf(-gv0)));
    float a1 = o1[j] * rs * w[seg * 8 + 4 + j] * (gv1 / (1.f + expf(-gv1)));
    r0[j] = f2b(a0);
    r1[j] = f2b(a1);
  }
  *(u16x4*)(onb + gbase) = r0;
  *(u16x4*)(onb + gbase + 4) = r1;
}

// ---------------- driver ----------------
extern "C" void kernel_launch(void* const* d_in, const int* in_sizes, int n_in,
                              void* d_out, int out_size, void* d_ws, size_t ws_size,
                              hipStream_t stream) {
  const float* x       = (const float*)d_in[0];
  const float* Wq      = (const float*)d_in[1];
  const float* Wk      = (const float*)d_in[2];
  const float* Wv      = (const float*)d_in[3];
  const float* cq      = (const float*)d_in[4];
  const float* ck      = (const float*)d_in[5];
  const float* cv      = (const float*)d_in[6];
  const float* Wf1     = (const float*)d_in[7];
  const float* Wf2     = (const float*)d_in[8];
  const float* Wb      = (const float*)d_in[9];
  const float* A_log   = (const float*)d_in[10];
  const float* dt_bias = (const float*)d_in[11];
  const float* Wg      = (const float*)d_in[12];
  const float* bg      = (const float*)d_in[13];
  const float* onw     = (const float*)d_in[14];
  const float* Wo      = (const float*)d_in[15];
  float* out = (float*)d_out;

  char* ws = (char*)d_ws;
  unsigned short* WT  = (unsigned short*)(ws);                       //  8 MB rotating W^T
  unsigned short* xb  = (unsigned short*)(ws + ((size_t)8  << 20));  // 16 MB bf16 x
  float* P    = (float*)(ws + ((size_t)24  << 20));                  // 32 MB rotating pre/gate
  float* qb   = (float*)(ws + ((size_t)56  << 20));                  // 32 MB [B,H,T,128]
  float* kb   = (float*)(ws + ((size_t)88  << 20));                  // 32 MB [B,H,T,128]
  float* vb   = (float*)(ws + ((size_t)120 << 20));                  // 32 MB (aliased by o)
  float* geb  = (float*)(ws + ((size_t)152 << 20));                  // 32 MB [B,H,T,128]
  float* betab= (float*)(ws + ((size_t)184 << 20));                  // 256 KB [B,H,T]
  float* f1   = (float*)(ws + ((size_t)185 << 20));                  //   2 MB
  unsigned short* f1b = (unsigned short*)(ws + ((size_t)187 << 20)); //   1 MB
  unsigned short* onb = xb;   // xb dead after gate GEMM
  float* gateb = P;           // P reused as gate buffer
  float* ob    = vb;          // scan output aliases v

  dim3 tb(32, 8);
  dim3 gemm_grid(HD / 128, MM / 128);

  cast_f32_bf16<<<(MM * DD / 4 + 255) / 256, 256, 0, stream>>>(x, xb, MM * DD / 4);

  // q path (scan scale 128^-0.5 folded into l2norm)
  transpose_cast<<<dim3(HD / 32, DD / 32), tb, 0, stream>>>(Wq, WT, DD, HD);
  gemm_bf16<<<gemm_grid, 256, 0, stream>>>(xb, WT, P, nullptr, MM, HD, DD);
  conv_silu_kernel<<<MM, 256, 0, stream>>>(P, cq, qb, 1, 0.08838834764831845f);
  // k path
  transpose_cast<<<dim3(HD / 32, DD / 32), tb, 0, stream>>>(Wk, WT, DD, HD);
  gemm_bf16<<<gemm_grid, 256, 0, stream>>>(xb, WT, P, nullptr, MM, HD, DD);
  conv_silu_kernel<<<MM, 256, 0, stream>>>(P, ck, kb, 1, 1.0f);
  // v path
  transpose_cast<<<dim3(HD / 32, DD / 32), tb, 0, stream>>>(Wv, WT, DD, HD);
  gemm_bf16<<<gemm_grid, 256, 0, stream>>>(xb, WT, P, nullptr, MM, HD, DD);
  conv_silu_kernel<<<MM, 256, 0, stream>>>(P, cv, vb, 0, 1.0f);

  // beta
  beta_kernel<<<MM, 256, 0, stream>>>(x, Wb, betab);

  // g chain
  transpose_cast<<<dim3(128 / 32, DD / 32), tb, 0, stream>>>(Wf1, WT, DD, 128);
  gemm_bf16<<<dim3(1, MM / 128), 256, 0, stream>>>(xb, WT, f1, nullptr, MM, 128, DD);
  cast_f32_bf16<<<(MM * 128 / 4 + 255) / 256, 256, 0, stream>>>(f1, f1b, MM * 128 / 4);
  transpose_cast<<<dim3(HD / 32, 128 / 32), tb, 0, stream>>>(Wf2, WT, 128, HD);
  gemm_bf16<<<gemm_grid, 256, 0, stream>>>(f1b, WT, P, nullptr, MM, HD, 128);
  gexp_kernel<<<(MM * HD + 255) / 256, 256, 0, stream>>>(P, A_log, dt_bias, geb, MM * HD);

  // gate = x@Wg + bg
  transpose_cast<<<dim3(HD / 32, DD / 32), tb, 0, stream>>>(Wg, WT, DD, HD);
  gemm_bf16<<<gemm_grid, 256, 0, stream>>>(xb, WT, gateb, bg, MM, HD, DD);

  // chunked-pipeline delta-rule scan (builtin DPP reduce + pinned prefetch)
  scan_kernel<<<BB * HH * 8, 256, 0, stream>>>(qb, kb, vb, geb, betab, ob);

  // gated RMSNorm -> bf16
  out_norm_kernel<<<MM, 256, 0, stream>>>(ob, gateb, onw, onb);

  // final projection
  transpose_cast<<<dim3(DD / 32, HD / 32), tb, 0, stream>>>(Wo, WT, HD, DD);
  gemm_bf16<<<dim3(DD / 128, MM / 128), 256, 0, stream>>>(onb, WT, out, nullptr, MM, DD, HD);
}